// Round 1
// baseline (4359.941 us; speedup 1.0000x reference)
//
#include <hip/hip_runtime.h>
#include <cstdint>
#include <cstddef>

#define NB 4
#define HH 96
#define WW 96
#define CHN 256
#define CC 64
#define LL 9216
#define NHASH 4
#define HBK 64
#define CHK 144
#define NCHUNK 64
#define NJ 36864   // NHASH * LL

// ---------------------------------------------------------------- conv 3x3 SAME
// tile: 64 pixels x 64 couts, 256 threads, each thread 4px x 4co
__global__ __launch_bounds__(256) void conv3x3_k(
    const float* __restrict__ in, const float* __restrict__ wgt,
    const float* __restrict__ bias, float* __restrict__ out, int CO)
{
    __shared__ float inb[64][36];   // 64 px x 32 ci, pad to 36
    __shared__ float wb[32][68];    // 32 ci x 64 co, pad to 68
    const int n = blockIdx.z;
    const int p0 = blockIdx.x * 64;
    const int co0 = blockIdx.y * 64;
    const int tid = threadIdx.x;
    const int cg = tid & 15;
    const int pg = tid >> 4;
    float acc[4][4];
#pragma unroll
    for (int a = 0; a < 4; a++)
#pragma unroll
        for (int b = 0; b < 4; b++) acc[a][b] = 0.f;
    const float* inN = in + (size_t)n * LL * CHN;
    for (int ky = 0; ky < 3; ky++)
    for (int kx = 0; kx < 3; kx++) {
        for (int ci0 = 0; ci0 < CHN; ci0 += 32) {
#pragma unroll
            for (int ld = 0; ld < 2; ld++) {
                int lin = tid * 2 + ld;
                int px = lin >> 3;
                int c4 = (lin & 7) * 4;
                int p = p0 + px;
                int hh = p / WW + ky - 1;
                int ww2 = p % WW + kx - 1;
                float4 v = make_float4(0.f, 0.f, 0.f, 0.f);
                if (hh >= 0 && hh < HH && ww2 >= 0 && ww2 < WW)
                    v = *(const float4*)(inN + (size_t)(hh * WW + ww2) * CHN + ci0 + c4);
                *(float4*)&inb[px][c4] = v;
            }
#pragma unroll
            for (int ld = 0; ld < 2; ld++) {
                int lin = tid * 2 + ld;
                int ci = lin >> 4;
                int c4 = (lin & 15) * 4;
                float4 v = *(const float4*)(wgt + (size_t)((ky * 3 + kx) * CHN + ci0 + ci) * CO + co0 + c4);
                *(float4*)&wb[ci][c4] = v;
            }
            __syncthreads();
#pragma unroll
            for (int s = 0; s < 8; s++) {
                int ci = s * 4;
                float4 bv0 = *(float4*)&wb[ci + 0][cg * 4];
                float4 bv1 = *(float4*)&wb[ci + 1][cg * 4];
                float4 bv2 = *(float4*)&wb[ci + 2][cg * 4];
                float4 bv3 = *(float4*)&wb[ci + 3][cg * 4];
#pragma unroll
                for (int k = 0; k < 4; k++) {
                    float4 av = *(float4*)&inb[pg * 4 + k][ci];
                    acc[k][0] = fmaf(av.x, bv0.x, fmaf(av.y, bv1.x, fmaf(av.z, bv2.x, fmaf(av.w, bv3.x, acc[k][0]))));
                    acc[k][1] = fmaf(av.x, bv0.y, fmaf(av.y, bv1.y, fmaf(av.z, bv2.y, fmaf(av.w, bv3.y, acc[k][1]))));
                    acc[k][2] = fmaf(av.x, bv0.z, fmaf(av.y, bv1.z, fmaf(av.z, bv2.z, fmaf(av.w, bv3.z, acc[k][2]))));
                    acc[k][3] = fmaf(av.x, bv0.w, fmaf(av.y, bv1.w, fmaf(av.z, bv2.w, fmaf(av.w, bv3.w, acc[k][3]))));
                }
            }
            __syncthreads();
        }
    }
    float* outN = out + (size_t)n * LL * CO;
#pragma unroll
    for (int k = 0; k < 4; k++) {
        int p = p0 + pg * 4 + k;
        float4 o;
        o.x = acc[k][0] + bias[co0 + cg * 4 + 0];
        o.y = acc[k][1] + bias[co0 + cg * 4 + 1];
        o.z = acc[k][2] + bias[co0 + cg * 4 + 2];
        o.w = acc[k][3] + bias[co0 + cg * 4 + 3];
        *(float4*)(outN + (size_t)p * CO + co0 + cg * 4) = o;
    }
}

// ---------------------------------------------------------------- transpose [R][Cc] -> [Cc][R], per batch
__global__ __launch_bounds__(256) void transpose_k(const float* __restrict__ in, float* __restrict__ out,
                                                   int R, int Cc)
{
    __shared__ float tl[32][33];
    const int n = blockIdx.z;
    const size_t base = (size_t)n * R * Cc;
    int c0 = blockIdx.x * 32, r0 = blockIdx.y * 32;
    int tx = threadIdx.x & 31, ty0 = threadIdx.x >> 5;
#pragma unroll
    for (int i = 0; i < 32; i += 8)
        tl[ty0 + i][tx] = in[base + (size_t)(r0 + ty0 + i) * Cc + c0 + tx];
    __syncthreads();
#pragma unroll
    for (int i = 0; i < 32; i += 8)
        out[base + (size_t)(c0 + ty0 + i) * R + r0 + tx] = tl[tx][ty0 + i];
}

// ---------------------------------------------------------------- hashing: codes + norm factors
__global__ __launch_bounds__(256) void hash_k(const float* __restrict__ xmT, const float* __restrict__ rot,
                                              int* __restrict__ codes, float* __restrict__ normf)
{
    __shared__ float rs[8192];  // rotations: (64, 4, 32)
    for (int e = threadIdx.x; e < 8192; e += 256) rs[e] = rot[e];
    __syncthreads();
    int g = blockIdx.x * 256 + threadIdx.x;   // grid exact: NB*LL
    int n = g / LL, t = g % LL;
    float x[64];
    const float* src = xmT + (size_t)g * CC;
#pragma unroll
    for (int f4 = 0; f4 < 16; f4++) {
        float4 v = *(const float4*)(src + f4 * 4);
        x[f4 * 4 + 0] = v.x; x[f4 * 4 + 1] = v.y; x[f4 * 4 + 2] = v.z; x[f4 * 4 + 3] = v.w;
    }
    float ss = 0.f;
#pragma unroll
    for (int f = 0; f < 64; f++) ss += x[f] * x[f];
    normf[g] = rsqrtf(fmaxf(ss, 5e-5f));
    for (int h = 0; h < NHASH; h++) {
        float bp = -1e30f, bn = -1e30f;
        int ip = 0, inn = 0;
        for (int i = 0; i < 32; i++) {
            float d = 0.f;
#pragma unroll
            for (int f = 0; f < 64; f++) d = fmaf(x[f], rs[f * 128 + h * 32 + i], d);
            if (d > bp) { bp = d; ip = i; }
            if (-d > bn) { bn = -d; inn = i; }
        }
        int code = (bp >= bn) ? ip : (32 + inn);   // first-max semantics over [rot, -rot]
        codes[(size_t)n * NJ + h * LL + t] = code + h * HBK;
    }
}

// ---------------------------------------------------------------- stable counting sort (256 buckets)
__global__ __launch_bounds__(256) void sort_hist_k(const int* __restrict__ codes, int* __restrict__ hist,
                                                   int* __restrict__ rank)
{
    __shared__ int lc[256];
    __shared__ int lh[256];
    const int n = blockIdx.y, seg = blockIdx.x, tid = threadIdx.x;
    int j = seg * 256 + tid;
    int c = codes[(size_t)n * NJ + j];
    lc[tid] = c;
    lh[tid] = 0;
    __syncthreads();
    int r = 0;
    for (int q = 0; q < tid; q++) r += (lc[q] == c) ? 1 : 0;
    atomicAdd(&lh[c], 1);
    __syncthreads();
    rank[(size_t)n * NJ + j] = r;
    hist[(size_t)n * NJ + tid * 144 + seg] = lh[tid];   // hist[n][key][seg]
}

__global__ __launch_bounds__(256) void sort_scan_k(int* __restrict__ hist)
{
    const int n = blockIdx.x;
    const int key = threadIdx.x;
    int* hn = hist + (size_t)n * NJ;
    int sum = 0;
    for (int s = 0; s < 144; s++) sum += hn[key * 144 + s];
    __shared__ int tot[256];
    tot[key] = sum;
    __syncthreads();
    int excl = 0;
    for (int q = 0; q < key; q++) excl += tot[q];
    int run = excl;
    for (int s = 0; s < 144; s++) { int v = hn[key * 144 + s]; hn[key * 144 + s] = run; run += v; }
}

__global__ __launch_bounds__(256) void sort_scatter_k(const int* __restrict__ codes, const int* __restrict__ rank,
                                                      const int* __restrict__ hist, int* __restrict__ sidx)
{
    const int n = blockIdx.y, seg = blockIdx.x, tid = threadIdx.x;
    int j = seg * 256 + tid;
    int c = codes[(size_t)n * NJ + j];
    int dest = hist[(size_t)n * NJ + c * 144 + seg] + rank[(size_t)n * NJ + j];
    sidx[(size_t)n * NJ + dest] = j;
}

// ---------------------------------------------------------------- attention helpers
__device__ __forceinline__ float dot64(const float q[64], const float* __restrict__ k)
{
    float s0 = 0.f, s1 = 0.f, s2 = 0.f, s3 = 0.f;
#pragma unroll
    for (int f = 0; f < 64; f += 4) {
        float4 kv = *(const float4*)(k + f);
        s0 = fmaf(q[f + 0], kv.x, s0);
        s1 = fmaf(q[f + 1], kv.y, s1);
        s2 = fmaf(q[f + 2], kv.z, s2);
        s3 = fmaf(q[f + 3], kv.w, s3);
    }
    return (s0 + s1) + (s2 + s3);
}

// pass 1: lse per sorted row -> bs (unsorted (h,t) space)
__global__ __launch_bounds__(576) void attn_lse_k(const float* __restrict__ xmT, const float* __restrict__ normf,
                                                  const int* __restrict__ sidx, float* __restrict__ bs)
{
    __shared__ float Ks[24][68];
    __shared__ float redm[144][4];
    __shared__ float redl[144][4];
    const int k = blockIdx.x, h = blockIdx.y, n = blockIdx.z;
    const int tid = threadIdx.x;
    const int i = tid >> 2, eg = tid & 3;
    const int* idxn = sidx + (size_t)n * NJ;
    const int sq = h * LL + k * CHK + i;
    const int jq = idxn[sq];
    const int tq = jq % LL;
    float q[64];
    {
        const float* src = xmT + ((size_t)n * LL + tq) * CC;
#pragma unroll
        for (int f4 = 0; f4 < 16; f4++) {
            float4 v = *(const float4*)(src + f4 * 4);
            q[f4 * 4 + 0] = v.x; q[f4 * 4 + 1] = v.y; q[f4 * 4 + 2] = v.z; q[f4 * 4 + 3] = v.w;
        }
    }
    float m = -1e30f, l = 0.f;
    for (int cc = 0; cc < 3; cc++) {
        int c = (cc == 0) ? k : (cc == 1 ? (k + NCHUNK - 1) & 63 : (k + 1) & 63);
        int sbase = h * LL + c * CHK;
        for (int tile = 0; tile < 6; tile++) {
            __syncthreads();
            for (int e = tid; e < 24 * 64; e += 576) {
                int rr = e >> 6, f = e & 63;
                int s2 = sbase + tile * 24 + rr;
                int t2 = idxn[s2] % LL;
                Ks[rr][f] = xmT[((size_t)n * LL + t2) * CC + f] * normf[(size_t)n * LL + t2];
            }
            __syncthreads();
#pragma unroll
            for (int jj = 0; jj < 6; jj++) {
                int r = eg * 6 + jj;
                float d = dot64(q, &Ks[r][0]);
                float nm = fmaxf(m, d);
                l = l * __expf(m - nm) + __expf(d - nm);
                m = nm;
            }
        }
    }
    redm[i][eg] = m;
    redl[i][eg] = l;
    __syncthreads();
    if (eg == 0) {
        float m0 = redm[i][0], m1 = redm[i][1], m2 = redm[i][2], m3 = redm[i][3];
        float mm = fmaxf(fmaxf(m0, m1), fmaxf(m2, m3));
        float ll = redl[i][0] * __expf(m0 - mm) + redl[i][1] * __expf(m1 - mm)
                 + redl[i][2] * __expf(m2 - mm) + redl[i][3] * __expf(m3 - mm);
        bs[(size_t)n * NJ + jq] = mm + __logf(ll);
    }
}

// softmax over the 4 hashes
__global__ __launch_bounds__(256) void probs_k(const float* __restrict__ bs, float* __restrict__ pr)
{
    int g = blockIdx.x * 256 + threadIdx.x;   // grid exact: NB*LL
    int n = g / LL, t = g % LL;
    const float* b = bs + (size_t)n * NJ;
    float b0 = b[0 * LL + t], b1 = b[1 * LL + t], b2 = b[2 * LL + t], b3 = b[3 * LL + t];
    float mx = fmaxf(fmaxf(b0, b1), fmaxf(b2, b3));
    float e0 = __expf(b0 - mx), e1 = __expf(b1 - mx), e2 = __expf(b2 - mx), e3 = __expf(b3 - mx);
    float inv = 1.f / (e0 + e1 + e2 + e3);
    float* p = pr + (size_t)n * NJ;
    p[0 * LL + t] = e0 * inv;
    p[1 * LL + t] = e1 * inv;
    p[2 * LL + t] = e2 * inv;
    p[3 * LL + t] = e3 * inv;
}

// pass 2: scores -> O, weighted by per-hash prob, atomically accumulated in (t,e) space
__global__ __launch_bounds__(576) void attn_out_k(const float* __restrict__ xmT, const float* __restrict__ yaT,
                                                  const float* __restrict__ normf, const int* __restrict__ sidx,
                                                  const float* __restrict__ bs, const float* __restrict__ probs,
                                                  float* __restrict__ accum)
{
    __shared__ float Ks[24][68];
    __shared__ float Ps[24][144];
    __shared__ float Vs[24][272];   // 4 segments of 64, strided 68 for bank spread
    const int k = blockIdx.x, h = blockIdx.y, n = blockIdx.z;
    const int tid = threadIdx.x;
    const int i = tid >> 2, eg = tid & 3;
    const int* idxn = sidx + (size_t)n * NJ;
    const int sq = h * LL + k * CHK + i;
    const int jq = idxn[sq];
    const int tq = jq % LL;
    float q[64];
    {
        const float* src = xmT + ((size_t)n * LL + tq) * CC;
#pragma unroll
        for (int f4 = 0; f4 < 16; f4++) {
            float4 v = *(const float4*)(src + f4 * 4);
            q[f4 * 4 + 0] = v.x; q[f4 * 4 + 1] = v.y; q[f4 * 4 + 2] = v.z; q[f4 * 4 + 3] = v.w;
        }
    }
    const float lse = bs[(size_t)n * NJ + jq];
    const float prw = probs[(size_t)n * NJ + jq];
    float acc[64];
#pragma unroll
    for (int f = 0; f < 64; f++) acc[f] = 0.f;
    for (int cc = 0; cc < 3; cc++) {
        int c = (cc == 0) ? k : (cc == 1 ? (k + NCHUNK - 1) & 63 : (k + 1) & 63);
        int sbase = h * LL + c * CHK;
        for (int tile = 0; tile < 6; tile++) {
            __syncthreads();
            for (int e = tid; e < 24 * 64; e += 576) {
                int rr = e >> 6, f = e & 63;
                int s2 = sbase + tile * 24 + rr;
                int t2 = idxn[s2] % LL;
                Ks[rr][f] = xmT[((size_t)n * LL + t2) * CC + f] * normf[(size_t)n * LL + t2];
            }
            for (int e = tid; e < 24 * 256; e += 576) {
                int rr = e >> 8, ee = e & 255;
                int s2 = sbase + tile * 24 + rr;
                int t2 = idxn[s2] % LL;
                Vs[rr][(ee >> 6) * 68 + (ee & 63)] = yaT[((size_t)n * LL + t2) * CHN + ee];
            }
            __syncthreads();
#pragma unroll
            for (int jj = 0; jj < 6; jj++) {
                int r = eg * 6 + jj;
                float d = dot64(q, &Ks[r][0]);
                Ps[r][i] = __expf(d - lse);
            }
            __syncthreads();
#pragma unroll
            for (int r = 0; r < 24; r++) {
                float p = Ps[r][i];
                const float* v = &Vs[r][eg * 68];
#pragma unroll
                for (int f = 0; f < 64; f += 4) {
                    float4 vv = *(const float4*)(v + f);
                    acc[f + 0] = fmaf(p, vv.x, acc[f + 0]);
                    acc[f + 1] = fmaf(p, vv.y, acc[f + 1]);
                    acc[f + 2] = fmaf(p, vv.z, acc[f + 2]);
                    acc[f + 3] = fmaf(p, vv.w, acc[f + 3]);
                }
            }
        }
    }
    float* dst = accum + ((size_t)n * LL + tq) * CHN + eg * 64;
#pragma unroll
    for (int f = 0; f < 64; f++) atomicAdd(dst + f, prw * acc[f]);
}

// ---------------------------------------------------------------- final: transpose back + residual + scale
__global__ __launch_bounds__(256) void final_k(const float* __restrict__ accum, const float* __restrict__ inp,
                                               float* __restrict__ out)
{
    __shared__ float tl[32][33];
    const int n = blockIdx.z;
    int t0 = blockIdx.x * 32, e0 = blockIdx.y * 32;
    int tx = threadIdx.x & 31, ty0 = threadIdx.x >> 5;
    const float* an = accum + (size_t)n * LL * CHN;
#pragma unroll
    for (int i = 0; i < 32; i += 8)
        tl[ty0 + i][tx] = an[(size_t)(t0 + ty0 + i) * CHN + e0 + tx];
    __syncthreads();
    const float* in_n = inp + (size_t)n * LL * CHN;
    float* on = out + (size_t)n * LL * CHN;
#pragma unroll
    for (int i = 0; i < 32; i += 8) {
        size_t o = (size_t)(e0 + ty0 + i) * LL + t0 + tx;
        on[o] = tl[tx][ty0 + i] * 0.1f + in_n[o];
    }
}

// ---------------------------------------------------------------- launch
extern "C" void kernel_launch(void* const* d_in, const int* in_sizes, int n_in,
                              void* d_out, int out_size, void* d_ws, size_t ws_size,
                              hipStream_t stream)
{
    (void)in_sizes; (void)n_in; (void)out_size; (void)ws_size;
    const float* input   = (const float*)d_in[0];
    const float* w_match = (const float*)d_in[1];
    const float* b_match = (const float*)d_in[2];
    const float* w_asm   = (const float*)d_in[3];
    const float* b_asm   = (const float*)d_in[4];
    const float* rot     = (const float*)d_in[5];
    float* out = (float*)d_out;

    char* ws = (char*)d_ws;
    size_t off = 0;
    auto alloc = [&](size_t elems) -> void* {
        void* p = ws + off;
        off += ((elems * 4 + 255) / 256) * 256;
        return p;
    };
    float* xm    = (float*)alloc((size_t)NB * LL * CC);
    float* ya    = (float*)alloc((size_t)NB * LL * CHN);
    float* xmT   = (float*)alloc((size_t)NB * LL * CC);
    float* yaT   = (float*)alloc((size_t)NB * LL * CHN);
    float* nrm   = (float*)alloc((size_t)NB * LL);
    int*   codes = (int*)  alloc((size_t)NB * NJ);
    int*   rank  = (int*)  alloc((size_t)NB * NJ);
    int*   hist  = (int*)  alloc((size_t)NB * NJ);
    int*   sidx  = (int*)  alloc((size_t)NB * NJ);
    float* bs    = (float*)alloc((size_t)NB * NJ);
    float* pr    = (float*)alloc((size_t)NB * NJ);
    float* accum = (float*)alloc((size_t)NB * LL * CHN);

    conv3x3_k<<<dim3(144, 1, NB), 256, 0, stream>>>(input, w_match, b_match, xm, CC);
    conv3x3_k<<<dim3(144, 4, NB), 256, 0, stream>>>(input, w_asm, b_asm, ya, CHN);
    transpose_k<<<dim3(288, 2, NB), 256, 0, stream>>>(xm, xmT, CC, LL);
    transpose_k<<<dim3(288, 8, NB), 256, 0, stream>>>(ya, yaT, CHN, LL);
    hash_k<<<dim3(144), 256, 0, stream>>>(xmT, rot, codes, nrm);
    sort_hist_k<<<dim3(144, NB), 256, 0, stream>>>(codes, hist, rank);
    sort_scan_k<<<dim3(NB), 256, 0, stream>>>(hist);
    sort_scatter_k<<<dim3(144, NB), 256, 0, stream>>>(codes, rank, hist, sidx);
    attn_lse_k<<<dim3(64, 4, NB), 576, 0, stream>>>(xmT, nrm, sidx, bs);
    probs_k<<<dim3(144), 256, 0, stream>>>(bs, pr);
    hipMemsetAsync(accum, 0, (size_t)NB * LL * CHN * sizeof(float), stream);
    attn_out_k<<<dim3(64, 4, NB), 576, 0, stream>>>(xmT, yaT, nrm, sidx, bs, pr, accum);
    final_k<<<dim3(288, 8, NB), 256, 0, stream>>>(accum, input, out);
}

// Round 2
// 1704.144 us; speedup vs baseline: 2.5584x; 2.5584x over previous
//
#include <hip/hip_runtime.h>
#include <cstdint>
#include <cstddef>

#define NB 4
#define HH 96
#define WW 96
#define CHN 256
#define CC 64
#define LL 9216
#define NHASH 4
#define HBK 64
#define CHK 144
#define NCHUNK 64
#define NJ 36864   // NHASH * LL

// ---------------------------------------------------------------- conv 3x3 SAME
__global__ __launch_bounds__(256) void conv3x3_k(
    const float* __restrict__ in, const float* __restrict__ wgt,
    const float* __restrict__ bias, float* __restrict__ out, int CO)
{
    __shared__ float inb[64][36];
    __shared__ float wb[32][68];
    const int n = blockIdx.z;
    const int p0 = blockIdx.x * 64;
    const int co0 = blockIdx.y * 64;
    const int tid = threadIdx.x;
    const int cg = tid & 15;
    const int pg = tid >> 4;
    float acc[4][4];
#pragma unroll
    for (int a = 0; a < 4; a++)
#pragma unroll
        for (int b = 0; b < 4; b++) acc[a][b] = 0.f;
    const float* inN = in + (size_t)n * LL * CHN;
    for (int ky = 0; ky < 3; ky++)
    for (int kx = 0; kx < 3; kx++) {
        for (int ci0 = 0; ci0 < CHN; ci0 += 32) {
#pragma unroll
            for (int ld = 0; ld < 2; ld++) {
                int lin = tid * 2 + ld;
                int px = lin >> 3;
                int c4 = (lin & 7) * 4;
                int p = p0 + px;
                int hh = p / WW + ky - 1;
                int ww2 = p % WW + kx - 1;
                float4 v = make_float4(0.f, 0.f, 0.f, 0.f);
                if (hh >= 0 && hh < HH && ww2 >= 0 && ww2 < WW)
                    v = *(const float4*)(inN + (size_t)(hh * WW + ww2) * CHN + ci0 + c4);
                *(float4*)&inb[px][c4] = v;
            }
#pragma unroll
            for (int ld = 0; ld < 2; ld++) {
                int lin = tid * 2 + ld;
                int ci = lin >> 4;
                int c4 = (lin & 15) * 4;
                float4 v = *(const float4*)(wgt + (size_t)((ky * 3 + kx) * CHN + ci0 + ci) * CO + co0 + c4);
                *(float4*)&wb[ci][c4] = v;
            }
            __syncthreads();
#pragma unroll
            for (int s = 0; s < 8; s++) {
                int ci = s * 4;
                float4 bv0 = *(float4*)&wb[ci + 0][cg * 4];
                float4 bv1 = *(float4*)&wb[ci + 1][cg * 4];
                float4 bv2 = *(float4*)&wb[ci + 2][cg * 4];
                float4 bv3 = *(float4*)&wb[ci + 3][cg * 4];
#pragma unroll
                for (int k = 0; k < 4; k++) {
                    float4 av = *(float4*)&inb[pg * 4 + k][ci];
                    acc[k][0] = fmaf(av.x, bv0.x, fmaf(av.y, bv1.x, fmaf(av.z, bv2.x, fmaf(av.w, bv3.x, acc[k][0]))));
                    acc[k][1] = fmaf(av.x, bv0.y, fmaf(av.y, bv1.y, fmaf(av.z, bv2.y, fmaf(av.w, bv3.y, acc[k][1]))));
                    acc[k][2] = fmaf(av.x, bv0.z, fmaf(av.y, bv1.z, fmaf(av.z, bv2.z, fmaf(av.w, bv3.z, acc[k][2]))));
                    acc[k][3] = fmaf(av.x, bv0.w, fmaf(av.y, bv1.w, fmaf(av.z, bv2.w, fmaf(av.w, bv3.w, acc[k][3]))));
                }
            }
            __syncthreads();
        }
    }
    float* outN = out + (size_t)n * LL * CO;
#pragma unroll
    for (int k = 0; k < 4; k++) {
        int p = p0 + pg * 4 + k;
        float4 o;
        o.x = acc[k][0] + bias[co0 + cg * 4 + 0];
        o.y = acc[k][1] + bias[co0 + cg * 4 + 1];
        o.z = acc[k][2] + bias[co0 + cg * 4 + 2];
        o.w = acc[k][3] + bias[co0 + cg * 4 + 3];
        *(float4*)(outN + (size_t)p * CO + co0 + cg * 4) = o;
    }
}

// ---------------------------------------------------------------- transpose [R][Cc] -> [Cc][R], per batch
__global__ __launch_bounds__(256) void transpose_k(const float* __restrict__ in, float* __restrict__ out,
                                                   int R, int Cc)
{
    __shared__ float tl[32][33];
    const int n = blockIdx.z;
    const size_t base = (size_t)n * R * Cc;
    int c0 = blockIdx.x * 32, r0 = blockIdx.y * 32;
    int tx = threadIdx.x & 31, ty0 = threadIdx.x >> 5;
#pragma unroll
    for (int i = 0; i < 32; i += 8)
        tl[ty0 + i][tx] = in[base + (size_t)(r0 + ty0 + i) * Cc + c0 + tx];
    __syncthreads();
#pragma unroll
    for (int i = 0; i < 32; i += 8)
        out[base + (size_t)(c0 + ty0 + i) * R + r0 + tx] = tl[tx][ty0 + i];
}

// ---------------------------------------------------------------- hashing: codes + squared norms
__global__ __launch_bounds__(256) void hash_k(const float* __restrict__ xmT, const float* __restrict__ rot,
                                              int* __restrict__ codes, float* __restrict__ ssq)
{
    __shared__ float rs[8192];  // rotations: (64, 4, 32)
    for (int e = threadIdx.x; e < 8192; e += 256) rs[e] = rot[e];
    __syncthreads();
    int g = blockIdx.x * 256 + threadIdx.x;   // grid exact: NB*LL
    int n = g / LL, t = g % LL;
    float x[64];
    const float* src = xmT + (size_t)g * CC;
#pragma unroll
    for (int f4 = 0; f4 < 16; f4++) {
        float4 v = *(const float4*)(src + f4 * 4);
        x[f4 * 4 + 0] = v.x; x[f4 * 4 + 1] = v.y; x[f4 * 4 + 2] = v.z; x[f4 * 4 + 3] = v.w;
    }
    float ss = 0.f;
#pragma unroll
    for (int f = 0; f < 64; f++) ss += x[f] * x[f];
    ssq[g] = ss;
    for (int h = 0; h < NHASH; h++) {
        float bp = -1e30f, bn = -1e30f;
        int ip = 0, inn = 0;
        for (int i = 0; i < 32; i++) {
            float d = 0.f;
#pragma unroll
            for (int f = 0; f < 64; f++) d = fmaf(x[f], rs[f * 128 + h * 32 + i], d);
            if (d > bp) { bp = d; ip = i; }
            if (-d > bn) { bn = -d; inn = i; }
        }
        int code = (bp >= bn) ? ip : (32 + inn);
        codes[(size_t)n * NJ + h * LL + t] = code + h * HBK;
    }
}

// ---------------------------------------------------------------- stable counting sort (256 buckets)
__global__ __launch_bounds__(256) void sort_hist_k(const int* __restrict__ codes, int* __restrict__ hist,
                                                   int* __restrict__ rank)
{
    __shared__ int lc[256];
    __shared__ int lh[256];
    const int n = blockIdx.y, seg = blockIdx.x, tid = threadIdx.x;
    int j = seg * 256 + tid;
    int c = codes[(size_t)n * NJ + j];
    lc[tid] = c;
    lh[tid] = 0;
    __syncthreads();
    int r = 0;
    for (int q = 0; q < tid; q++) r += (lc[q] == c) ? 1 : 0;
    atomicAdd(&lh[c], 1);
    __syncthreads();
    rank[(size_t)n * NJ + j] = r;
    hist[(size_t)n * NJ + tid * 144 + seg] = lh[tid];
}

__global__ __launch_bounds__(256) void sort_scan_k(int* __restrict__ hist)
{
    const int n = blockIdx.x;
    const int key = threadIdx.x;
    int* hn = hist + (size_t)n * NJ;
    int sum = 0;
    for (int s = 0; s < 144; s++) sum += hn[key * 144 + s];
    __shared__ int tot[256];
    tot[key] = sum;
    __syncthreads();
    int excl = 0;
    for (int q = 0; q < key; q++) excl += tot[q];
    int run = excl;
    for (int s = 0; s < 144; s++) { int v = hn[key * 144 + s]; hn[key * 144 + s] = run; run += v; }
}

__global__ __launch_bounds__(256) void sort_scatter_k(const int* __restrict__ codes, const int* __restrict__ rank,
                                                      const int* __restrict__ hist, int* __restrict__ sidx,
                                                      int* __restrict__ undo)
{
    const int n = blockIdx.y, seg = blockIdx.x, tid = threadIdx.x;
    int j = seg * 256 + tid;
    int c = codes[(size_t)n * NJ + j];
    int dest = hist[(size_t)n * NJ + c * 144 + seg] + rank[(size_t)n * NJ + j];
    sidx[(size_t)n * NJ + dest] = j;
    undo[(size_t)n * NJ + j] = dest;
}

// ---------------------------------------------------------------- fused single-pass attention
// thread map: e16 = tid&15 (16-channel slab), qq = tid>>4 (4 queries each)
// score trick: raw = |q| * (khat_q . khat_key); fixed softmax max = |q| (valid upper bound)
__global__ __launch_bounds__(576) void attn_fused_k(
    const float* __restrict__ xmT, const float* __restrict__ yaT,
    const float* __restrict__ ssq, const int* __restrict__ sidx,
    float* __restrict__ Osort, float* __restrict__ bs)
{
    __shared__ float Kb[144][68];   // own chunk, normalized (queries AND self-keys)
    __shared__ float Ks[16][68];    // neighbor-chunk K tile
    __shared__ float Vs[16][320];   // V tile, 16-col groups at stride 20 (bank spread)
    __shared__ float Ps[16][148];   // P tile [key][query]
    __shared__ float redl[144][4];
    __shared__ float linv[144];
    __shared__ int   tIdx[432];
    __shared__ float nfs[432];

    const int k = blockIdx.x, h = blockIdx.y, n = blockIdx.z;
    const int tid = threadIdx.x;
    const int e16 = tid & 15, qq = tid >> 4;
    const size_t sbase = (size_t)n * NJ + (size_t)h * LL;

    int ck0 = k, ck1 = (k + NCHUNK - 1) & (NCHUNK - 1), ck2 = (k + 1) & (NCHUNK - 1);
    if (tid < 432) {
        int cc = tid / CHK, rr = tid - cc * CHK;
        int c = (cc == 0) ? ck0 : (cc == 1 ? ck1 : ck2);
        int j = sidx[sbase + c * CHK + rr];
        int t = j % LL;
        tIdx[tid] = t;
        float m = fmaxf(ssq[(size_t)n * LL + t], 5e-5f);
        nfs[tid] = rsqrtf(m);
    }
    __syncthreads();
    // stage Kb: 144 rows x 16 float4
    for (int e = tid; e < 144 * 16; e += 576) {
        int rr = e >> 4, f4 = e & 15;
        float4 v = *(const float4*)(xmT + ((size_t)n * LL + tIdx[rr]) * CC + f4 * 4);
        float nf = nfs[rr];
        v.x *= nf; v.y *= nf; v.z *= nf; v.w *= nf;
        *(float4*)&Kb[rr][f4 * 4] = v;
    }
    __syncthreads();

    const int myq = qq * 4 + (e16 & 3);
    const int kq0 = (e16 >> 2) * 4;
    const float ql = 1.0f / nfs[myq];   // |q| (with L2_EPS clamp; valid fixed max)
    float l = 0.f;
    float acc[4][16];
#pragma unroll
    for (int a = 0; a < 4; a++)
#pragma unroll
        for (int b = 0; b < 16; b++) acc[a][b] = 0.f;

    for (int cc = 0; cc < 3; cc++) {
        for (int tile = 0; tile < 9; tile++) {
            __syncthreads();
            const int rbase = cc * CHK + tile * 16;
            if (cc != 0 && tid < 256) {
                int rr = tid >> 4, f4 = tid & 15;
                float4 v = *(const float4*)(xmT + ((size_t)n * LL + tIdx[rbase + rr]) * CC + f4 * 4);
                float nf = nfs[rbase + rr];
                v.x *= nf; v.y *= nf; v.z *= nf; v.w *= nf;
                *(float4*)&Ks[rr][f4 * 4] = v;
            }
            for (int e = tid; e < 1024; e += 576) {
                int rr = e >> 6, f4 = e & 63;
                float4 v = *(const float4*)(yaT + ((size_t)n * LL + tIdx[rbase + rr]) * CHN + f4 * 4);
                *(float4*)&Vs[rr][(f4 >> 2) * 20 + (f4 & 3) * 4] = v;
            }
            __syncthreads();
            // QK: 4 dots per thread (query myq, keys kq0..kq0+3)
            {
                const float* kbq = &Kb[myq][0];
                const float (*Kt)[68] = (cc == 0) ? (const float(*)[68])(&Kb[tile * 16])
                                                  : (const float(*)[68])Ks;
                float d0 = 0.f, d1 = 0.f, d2 = 0.f, d3 = 0.f;
#pragma unroll
                for (int f = 0; f < 64; f += 4) {
                    float4 qv = *(const float4*)(kbq + f);
                    float4 k0 = *(const float4*)(&Kt[kq0 + 0][f]);
                    float4 k1 = *(const float4*)(&Kt[kq0 + 1][f]);
                    float4 k2 = *(const float4*)(&Kt[kq0 + 2][f]);
                    float4 k3 = *(const float4*)(&Kt[kq0 + 3][f]);
                    d0 = fmaf(qv.x, k0.x, fmaf(qv.y, k0.y, fmaf(qv.z, k0.z, fmaf(qv.w, k0.w, d0))));
                    d1 = fmaf(qv.x, k1.x, fmaf(qv.y, k1.y, fmaf(qv.z, k1.z, fmaf(qv.w, k1.w, d1))));
                    d2 = fmaf(qv.x, k2.x, fmaf(qv.y, k2.y, fmaf(qv.z, k2.z, fmaf(qv.w, k2.w, d2))));
                    d3 = fmaf(qv.x, k3.x, fmaf(qv.y, k3.y, fmaf(qv.z, k3.z, fmaf(qv.w, k3.w, d3))));
                }
                float p0 = __expf(ql * (d0 - 1.f));
                float p1 = __expf(ql * (d1 - 1.f));
                float p2 = __expf(ql * (d2 - 1.f));
                float p3 = __expf(ql * (d3 - 1.f));
                Ps[kq0 + 0][myq] = p0;
                Ps[kq0 + 1][myq] = p1;
                Ps[kq0 + 2][myq] = p2;
                Ps[kq0 + 3][myq] = p3;
                l += (p0 + p1) + (p2 + p3);
            }
            __syncthreads();
            // PV: 16 rows x 4 queries x 16 channels
#pragma unroll
            for (int r = 0; r < 16; r++) {
                const float p0 = Ps[r][qq * 4 + 0];
                const float p1 = Ps[r][qq * 4 + 1];
                const float p2 = Ps[r][qq * 4 + 2];
                const float p3 = Ps[r][qq * 4 + 3];
                const float* vp = &Vs[r][e16 * 20];
#pragma unroll
                for (int c4 = 0; c4 < 4; c4++) {
                    float4 vv = *(const float4*)(vp + c4 * 4);
                    acc[0][c4*4+0] = fmaf(p0, vv.x, acc[0][c4*4+0]);
                    acc[0][c4*4+1] = fmaf(p0, vv.y, acc[0][c4*4+1]);
                    acc[0][c4*4+2] = fmaf(p0, vv.z, acc[0][c4*4+2]);
                    acc[0][c4*4+3] = fmaf(p0, vv.w, acc[0][c4*4+3]);
                    acc[1][c4*4+0] = fmaf(p1, vv.x, acc[1][c4*4+0]);
                    acc[1][c4*4+1] = fmaf(p1, vv.y, acc[1][c4*4+1]);
                    acc[1][c4*4+2] = fmaf(p1, vv.z, acc[1][c4*4+2]);
                    acc[1][c4*4+3] = fmaf(p1, vv.w, acc[1][c4*4+3]);
                    acc[2][c4*4+0] = fmaf(p2, vv.x, acc[2][c4*4+0]);
                    acc[2][c4*4+1] = fmaf(p2, vv.y, acc[2][c4*4+1]);
                    acc[2][c4*4+2] = fmaf(p2, vv.z, acc[2][c4*4+2]);
                    acc[2][c4*4+3] = fmaf(p2, vv.w, acc[2][c4*4+3]);
                    acc[3][c4*4+0] = fmaf(p3, vv.x, acc[3][c4*4+0]);
                    acc[3][c4*4+1] = fmaf(p3, vv.y, acc[3][c4*4+1]);
                    acc[3][c4*4+2] = fmaf(p3, vv.z, acc[3][c4*4+2]);
                    acc[3][c4*4+3] = fmaf(p3, vv.w, acc[3][c4*4+3]);
                }
            }
        }
    }
    redl[myq][e16 >> 2] = l;
    __syncthreads();
    if (tid < 144) {
        float lt = redl[tid][0] + redl[tid][1] + redl[tid][2] + redl[tid][3];
        linv[tid] = 1.0f / lt;
        float qlt = 1.0f / nfs[tid];
        int jq = sidx[sbase + (size_t)k * CHK + tid];
        bs[(size_t)n * NJ + jq] = qlt + __logf(lt);
    }
    __syncthreads();
#pragma unroll
    for (int q = 0; q < 4; q++) {
        int query = qq * 4 + q;
        float inv = linv[query];
        float* od = Osort + (sbase + (size_t)k * CHK + query) * CHN + e16 * 16;
#pragma unroll
        for (int c4 = 0; c4 < 4; c4++) {
            float4 o;
            o.x = acc[q][c4*4+0] * inv;
            o.y = acc[q][c4*4+1] * inv;
            o.z = acc[q][c4*4+2] * inv;
            o.w = acc[q][c4*4+3] * inv;
            *(float4*)(od + c4 * 4) = o;
        }
    }
}

// ---------------------------------------------------------------- softmax over the 4 hashes
__global__ __launch_bounds__(256) void probs_k(const float* __restrict__ bs, float* __restrict__ pr)
{
    int g = blockIdx.x * 256 + threadIdx.x;
    int n = g / LL, t = g % LL;
    const float* b = bs + (size_t)n * NJ;
    float b0 = b[0 * LL + t], b1 = b[1 * LL + t], b2 = b[2 * LL + t], b3 = b[3 * LL + t];
    float mx = fmaxf(fmaxf(b0, b1), fmaxf(b2, b3));
    float e0 = __expf(b0 - mx), e1 = __expf(b1 - mx), e2 = __expf(b2 - mx), e3 = __expf(b3 - mx);
    float inv = 1.f / (e0 + e1 + e2 + e3);
    float* p = pr + (size_t)n * NJ;
    p[0 * LL + t] = e0 * inv;
    p[1 * LL + t] = e1 * inv;
    p[2 * LL + t] = e2 * inv;
    p[3 * LL + t] = e3 * inv;
}

// ---------------------------------------------------------------- combine 4 hashes -> accum[t][e]
__global__ __launch_bounds__(256) void combine_k(
    const float* __restrict__ Osort, const float* __restrict__ pr,
    const int* __restrict__ undo, float* __restrict__ accum)
{
    const int n = blockIdx.y;
    const int t0 = blockIdx.x * 64;   // grid.x = 144
    const int w = threadIdx.x >> 6, lane = threadIdx.x & 63;
    for (int tt = 0; tt < 16; tt++) {
        int t = t0 + w * 16 + tt;
        float4 a = make_float4(0.f, 0.f, 0.f, 0.f);
#pragma unroll
        for (int hh = 0; hh < 4; hh++) {
            int srow = undo[(size_t)n * NJ + hh * LL + t];
            float p = pr[(size_t)n * NJ + hh * LL + t];
            float4 v = *(const float4*)(Osort + ((size_t)n * NJ + srow) * CHN + lane * 4);
            a.x = fmaf(p, v.x, a.x); a.y = fmaf(p, v.y, a.y);
            a.z = fmaf(p, v.z, a.z); a.w = fmaf(p, v.w, a.w);
        }
        *(float4*)(accum + ((size_t)n * LL + t) * CHN + lane * 4) = a;
    }
}

// ---------------------------------------------------------------- final: transpose back + residual + scale
__global__ __launch_bounds__(256) void final_k(const float* __restrict__ accum, const float* __restrict__ inp,
                                               float* __restrict__ out)
{
    __shared__ float tl[32][33];
    const int n = blockIdx.z;
    int t0 = blockIdx.x * 32, e0 = blockIdx.y * 32;
    int tx = threadIdx.x & 31, ty0 = threadIdx.x >> 5;
    const float* an = accum + (size_t)n * LL * CHN;
#pragma unroll
    for (int i = 0; i < 32; i += 8)
        tl[ty0 + i][tx] = an[(size_t)(t0 + ty0 + i) * CHN + e0 + tx];
    __syncthreads();
    const float* in_n = inp + (size_t)n * LL * CHN;
    float* on = out + (size_t)n * LL * CHN;
#pragma unroll
    for (int i = 0; i < 32; i += 8) {
        size_t o = (size_t)(e0 + ty0 + i) * LL + t0 + tx;
        on[o] = tl[tx][ty0 + i] * 0.1f + in_n[o];
    }
}

// ---------------------------------------------------------------- launch
extern "C" void kernel_launch(void* const* d_in, const int* in_sizes, int n_in,
                              void* d_out, int out_size, void* d_ws, size_t ws_size,
                              hipStream_t stream)
{
    (void)in_sizes; (void)n_in; (void)out_size; (void)ws_size;
    const float* input   = (const float*)d_in[0];
    const float* w_match = (const float*)d_in[1];
    const float* b_match = (const float*)d_in[2];
    const float* w_asm   = (const float*)d_in[3];
    const float* b_asm   = (const float*)d_in[4];
    const float* rot     = (const float*)d_in[5];
    float* out = (float*)d_out;

    char* ws = (char*)d_ws;
    size_t off = 0;
    auto alloc = [&](size_t bytes) -> void* {
        void* p = ws + off;
        off += (bytes + 255) & ~(size_t)255;
        return p;
    };
    float* ya    = (float*)alloc((size_t)NB * LL * CHN * 4);   // reused as accum later
    float* yaT   = (float*)alloc((size_t)NB * LL * CHN * 4);
    float* xm    = (float*)alloc((size_t)NB * LL * CC * 4);
    float* xmT   = (float*)alloc((size_t)NB * LL * CC * 4);
    float* ssq   = (float*)alloc((size_t)NB * LL * 4);
    int*   codes = (int*)  alloc((size_t)NB * NJ * 4);
    int*   rank  = (int*)  alloc((size_t)NB * NJ * 4);
    int*   hist  = (int*)  alloc((size_t)NB * NJ * 4);
    int*   sidx  = (int*)  alloc((size_t)NB * NJ * 4);
    int*   undo  = (int*)  alloc((size_t)NB * NJ * 4);
    float* bs    = (float*)alloc((size_t)NB * NJ * 4);
    float* pr    = (float*)alloc((size_t)NB * NJ * 4);
    float* Osort = (float*)alloc((size_t)NB * NJ * CHN * 4);
    float* accum = ya;   // ya dead after its transpose; alias

    conv3x3_k<<<dim3(144, 1, NB), 256, 0, stream>>>(input, w_match, b_match, xm, CC);
    conv3x3_k<<<dim3(144, 4, NB), 256, 0, stream>>>(input, w_asm, b_asm, ya, CHN);
    transpose_k<<<dim3(288, 2, NB), 256, 0, stream>>>(xm, xmT, CC, LL);
    transpose_k<<<dim3(288, 8, NB), 256, 0, stream>>>(ya, yaT, CHN, LL);
    hash_k<<<dim3(144), 256, 0, stream>>>(xmT, rot, codes, ssq);
    sort_hist_k<<<dim3(144, NB), 256, 0, stream>>>(codes, hist, rank);
    sort_scan_k<<<dim3(NB), 256, 0, stream>>>(hist);
    sort_scatter_k<<<dim3(144, NB), 256, 0, stream>>>(codes, rank, hist, sidx, undo);
    attn_fused_k<<<dim3(64, 4, NB), 576, 0, stream>>>(xmT, yaT, ssq, sidx, Osort, bs);
    probs_k<<<dim3(144), 256, 0, stream>>>(bs, pr);
    combine_k<<<dim3(144, NB), 256, 0, stream>>>(Osort, pr, undo, accum);
    final_k<<<dim3(288, 8, NB), 256, 0, stream>>>(accum, input, out);
}

// Round 3
// 1211.905 us; speedup vs baseline: 3.5976x; 1.4062x over previous
//
#include <hip/hip_runtime.h>
#include <cstdint>
#include <cstddef>

#define NB 4
#define HH 96
#define WW 96
#define CHN 256
#define CC 64
#define LL 9216
#define NHASH 4
#define HBK 64
#define CHK 144
#define NCHUNK 64
#define NJ 36864   // NHASH * LL

typedef __attribute__((ext_vector_type(8))) short bf16x8;
typedef __attribute__((ext_vector_type(4))) float f32x4;

__device__ __forceinline__ unsigned short f2b(float f) {
    unsigned int x = __float_as_uint(f);
    x += 0x7FFFu + ((x >> 16) & 1u);
    return (unsigned short)(x >> 16);
}
__device__ __forceinline__ float b2f(unsigned short u) {
    return __uint_as_float(((unsigned int)u) << 16);
}

// ---------------------------------------------------------------- conv 3x3 SAME (fp32 — feeds hashing)
__global__ __launch_bounds__(256) void conv3x3_k(
    const float* __restrict__ in, const float* __restrict__ wgt,
    const float* __restrict__ bias, float* __restrict__ out, int CO)
{
    __shared__ float inb[64][36];
    __shared__ float wb[32][68];
    const int n = blockIdx.z;
    const int p0 = blockIdx.x * 64;
    const int co0 = blockIdx.y * 64;
    const int tid = threadIdx.x;
    const int cg = tid & 15;
    const int pg = tid >> 4;
    float acc[4][4];
#pragma unroll
    for (int a = 0; a < 4; a++)
#pragma unroll
        for (int b = 0; b < 4; b++) acc[a][b] = 0.f;
    const float* inN = in + (size_t)n * LL * CHN;
    for (int ky = 0; ky < 3; ky++)
    for (int kx = 0; kx < 3; kx++) {
        for (int ci0 = 0; ci0 < CHN; ci0 += 32) {
#pragma unroll
            for (int ld = 0; ld < 2; ld++) {
                int lin = tid * 2 + ld;
                int px = lin >> 3;
                int c4 = (lin & 7) * 4;
                int p = p0 + px;
                int hh = p / WW + ky - 1;
                int ww2 = p % WW + kx - 1;
                float4 v = make_float4(0.f, 0.f, 0.f, 0.f);
                if (hh >= 0 && hh < HH && ww2 >= 0 && ww2 < WW)
                    v = *(const float4*)(inN + (size_t)(hh * WW + ww2) * CHN + ci0 + c4);
                *(float4*)&inb[px][c4] = v;
            }
#pragma unroll
            for (int ld = 0; ld < 2; ld++) {
                int lin = tid * 2 + ld;
                int ci = lin >> 4;
                int c4 = (lin & 15) * 4;
                float4 v = *(const float4*)(wgt + (size_t)((ky * 3 + kx) * CHN + ci0 + ci) * CO + co0 + c4);
                *(float4*)&wb[ci][c4] = v;
            }
            __syncthreads();
#pragma unroll
            for (int s = 0; s < 8; s++) {
                int ci = s * 4;
                float4 bv0 = *(float4*)&wb[ci + 0][cg * 4];
                float4 bv1 = *(float4*)&wb[ci + 1][cg * 4];
                float4 bv2 = *(float4*)&wb[ci + 2][cg * 4];
                float4 bv3 = *(float4*)&wb[ci + 3][cg * 4];
#pragma unroll
                for (int k = 0; k < 4; k++) {
                    float4 av = *(float4*)&inb[pg * 4 + k][ci];
                    acc[k][0] = fmaf(av.x, bv0.x, fmaf(av.y, bv1.x, fmaf(av.z, bv2.x, fmaf(av.w, bv3.x, acc[k][0]))));
                    acc[k][1] = fmaf(av.x, bv0.y, fmaf(av.y, bv1.y, fmaf(av.z, bv2.y, fmaf(av.w, bv3.y, acc[k][1]))));
                    acc[k][2] = fmaf(av.x, bv0.z, fmaf(av.y, bv1.z, fmaf(av.z, bv2.z, fmaf(av.w, bv3.z, acc[k][2]))));
                    acc[k][3] = fmaf(av.x, bv0.w, fmaf(av.y, bv1.w, fmaf(av.z, bv2.w, fmaf(av.w, bv3.w, acc[k][3]))));
                }
            }
            __syncthreads();
        }
    }
    float* outN = out + (size_t)n * LL * CO;
#pragma unroll
    for (int k = 0; k < 4; k++) {
        int p = p0 + pg * 4 + k;
        float4 o;
        o.x = acc[k][0] + bias[co0 + cg * 4 + 0];
        o.y = acc[k][1] + bias[co0 + cg * 4 + 1];
        o.z = acc[k][2] + bias[co0 + cg * 4 + 2];
        o.w = acc[k][3] + bias[co0 + cg * 4 + 3];
        *(float4*)(outN + (size_t)p * CO + co0 + cg * 4) = o;
    }
}

// ---------------------------------------------------------------- transpose [R][Cc] -> [Cc][R], per batch
__global__ __launch_bounds__(256) void transpose_k(const float* __restrict__ in, float* __restrict__ out,
                                                   int R, int Cc)
{
    __shared__ float tl[32][33];
    const int n = blockIdx.z;
    const size_t base = (size_t)n * R * Cc;
    int c0 = blockIdx.x * 32, r0 = blockIdx.y * 32;
    int tx = threadIdx.x & 31, ty0 = threadIdx.x >> 5;
#pragma unroll
    for (int i = 0; i < 32; i += 8)
        tl[ty0 + i][tx] = in[base + (size_t)(r0 + ty0 + i) * Cc + c0 + tx];
    __syncthreads();
#pragma unroll
    for (int i = 0; i < 32; i += 8)
        out[base + (size_t)(c0 + ty0 + i) * R + r0 + tx] = tl[tx][ty0 + i];
}

// ---------------------------------------------------------------- hashing: codes + squared norms (fp32!)
__global__ __launch_bounds__(256) void hash_k(const float* __restrict__ xmT, const float* __restrict__ rot,
                                              int* __restrict__ codes, float* __restrict__ ssq)
{
    __shared__ float rs[8192];  // rotations: (64, 4, 32)
    for (int e = threadIdx.x; e < 8192; e += 256) rs[e] = rot[e];
    __syncthreads();
    int g = blockIdx.x * 256 + threadIdx.x;   // grid exact: NB*LL
    int n = g / LL, t = g % LL;
    float x[64];
    const float* src = xmT + (size_t)g * CC;
#pragma unroll
    for (int f4 = 0; f4 < 16; f4++) {
        float4 v = *(const float4*)(src + f4 * 4);
        x[f4 * 4 + 0] = v.x; x[f4 * 4 + 1] = v.y; x[f4 * 4 + 2] = v.z; x[f4 * 4 + 3] = v.w;
    }
    float ss = 0.f;
#pragma unroll
    for (int f = 0; f < 64; f++) ss += x[f] * x[f];
    ssq[g] = ss;
    for (int h = 0; h < NHASH; h++) {
        float bp = -1e30f, bn = -1e30f;
        int ip = 0, inn = 0;
        for (int i = 0; i < 32; i++) {
            float d = 0.f;
#pragma unroll
            for (int f = 0; f < 64; f++) d = fmaf(x[f], rs[f * 128 + h * 32 + i], d);
            if (d > bp) { bp = d; ip = i; }
            if (-d > bn) { bn = -d; inn = i; }
        }
        int code = (bp >= bn) ? ip : (32 + inn);
        codes[(size_t)n * NJ + h * LL + t] = code + h * HBK;
    }
}

// ---------------------------------------------------------------- stable counting sort (256 buckets)
__global__ __launch_bounds__(256) void sort_hist_k(const int* __restrict__ codes, int* __restrict__ hist,
                                                   int* __restrict__ rank)
{
    __shared__ int lc[256];
    __shared__ int lh[256];
    const int n = blockIdx.y, seg = blockIdx.x, tid = threadIdx.x;
    int j = seg * 256 + tid;
    int c = codes[(size_t)n * NJ + j];
    lc[tid] = c;
    lh[tid] = 0;
    __syncthreads();
    int r = 0;
    for (int q = 0; q < tid; q++) r += (lc[q] == c) ? 1 : 0;
    atomicAdd(&lh[c], 1);
    __syncthreads();
    rank[(size_t)n * NJ + j] = r;
    hist[(size_t)n * NJ + tid * 144 + seg] = lh[tid];
}

__global__ __launch_bounds__(256) void sort_scan_k(int* __restrict__ hist)
{
    const int n = blockIdx.x;
    const int key = threadIdx.x;
    int* hn = hist + (size_t)n * NJ;
    int sum = 0;
    for (int s = 0; s < 144; s++) sum += hn[key * 144 + s];
    __shared__ int tot[256];
    tot[key] = sum;
    __syncthreads();
    int excl = 0;
    for (int q = 0; q < key; q++) excl += tot[q];
    int run = excl;
    for (int s = 0; s < 144; s++) { int v = hn[key * 144 + s]; hn[key * 144 + s] = run; run += v; }
}

__global__ __launch_bounds__(256) void sort_scatter_k(const int* __restrict__ codes, const int* __restrict__ rank,
                                                      const int* __restrict__ hist, int* __restrict__ sidx,
                                                      int* __restrict__ undo)
{
    const int n = blockIdx.y, seg = blockIdx.x, tid = threadIdx.x;
    int j = seg * 256 + tid;
    int c = codes[(size_t)n * NJ + j];
    int dest = hist[(size_t)n * NJ + c * 144 + seg] + rank[(size_t)n * NJ + j];
    sidx[(size_t)n * NJ + dest] = j;
    undo[(size_t)n * NJ + j] = dest;
}

// ---------------------------------------------------------------- MFMA attention
// block = one (n, h, chunk k). 1024 threads = 16 waves.
// Q (unnormalized, bf16) 144x64; per chunk: K̂c bf16 144x64 (union w/ P), Vc bf16 160x256 (rows 144-159 zero),
// P bf16 144x160 (cols 144-159 zero). QK = mfma 16x16x32 (B^T GEMM); PV = mfma 16x16x32, K=160.
// softmax fixed max = |q| (clamped, valid upper bound) -> single pass; lse = |q| + log(sum).
#define QSTR 72     // Q/K row stride in shorts (144B)
#define PSTR 168    // P row stride in shorts (336B)
#define VSTR 264    // V row stride in shorts (528B)
__global__ __launch_bounds__(1024) void attn_mfma_k(
    const float* __restrict__ xmT, const float* __restrict__ yaT,
    const float* __restrict__ ssq, const int* __restrict__ sidx,
    unsigned short* __restrict__ Osort, float* __restrict__ bs)
{
    __shared__ short Qs[144 * QSTR];
    __shared__ short UN[144 * PSTR];    // K̂c (stride QSTR) then, after sync, P (stride PSTR)
    __shared__ short Vs[160 * VSTR];
    __shared__ int   tIdx[432];
    __shared__ float nfs[432];
    __shared__ float lsum[144];
    __shared__ float linv[144];

    const int k = blockIdx.x, h = blockIdx.y, n = blockIdx.z;
    const int tid = threadIdx.x;
    const int w = tid >> 6;             // wave 0..15
    const int lane = tid & 63;
    const int lm = lane & 15, lq = lane >> 4;
    const size_t sbase = (size_t)n * NJ + (size_t)h * LL;

    if (tid < 432) {
        int cc = tid / CHK, rr = tid - cc * CHK;
        int c = (cc == 0) ? k : (cc == 1 ? (k + NCHUNK - 1) & (NCHUNK - 1) : (k + 1) & (NCHUNK - 1));
        int j = sidx[sbase + c * CHK + rr];
        int t = j % LL;
        tIdx[tid] = t;
        nfs[tid] = rsqrtf(fmaxf(ssq[(size_t)n * LL + t], 5e-5f));
    }
    if (tid < 144) lsum[tid] = 0.f;
    __syncthreads();

    // stage Q (unnormalized bf16): 144 rows x 8 groups of 8 floats
    for (int e = tid; e < 1152; e += 1024) {
        int r = e >> 3, j8 = e & 7;
        const float* src = xmT + ((size_t)n * LL + tIdx[r]) * CC + j8 * 8;
        float4 v0 = *(const float4*)src, v1 = *(const float4*)(src + 4);
        short* d = &Qs[r * QSTR + j8 * 8];
        d[0] = (short)f2b(v0.x); d[1] = (short)f2b(v0.y); d[2] = (short)f2b(v0.z); d[3] = (short)f2b(v0.w);
        d[4] = (short)f2b(v1.x); d[5] = (short)f2b(v1.y); d[6] = (short)f2b(v1.z); d[7] = (short)f2b(v1.w);
    }

    const int et = w;                   // e-tile for PV (16 waves = 16 tiles of 16 channels)
    f32x4 accO[9];
#pragma unroll
    for (int mt = 0; mt < 9; mt++) accO[mt] = (f32x4){0.f, 0.f, 0.f, 0.f};
    float pbuf[6][4];                   // exp'd scores, max 6 QK tiles per wave

    for (int cc = 0; cc < 3; cc++) {
        __syncthreads();                // (a) prev chunk's PV done
        // stage K̂c into UN (stride QSTR), normalized
        for (int e = tid; e < 1152; e += 1024) {
            int r = e >> 3, j8 = e & 7;
            const float* src = xmT + ((size_t)n * LL + tIdx[cc * CHK + r]) * CC + j8 * 8;
            float nf = nfs[cc * CHK + r];
            float4 v0 = *(const float4*)src, v1 = *(const float4*)(src + 4);
            short* d = &UN[r * QSTR + j8 * 8];
            d[0] = (short)f2b(v0.x * nf); d[1] = (short)f2b(v0.y * nf);
            d[2] = (short)f2b(v0.z * nf); d[3] = (short)f2b(v0.w * nf);
            d[4] = (short)f2b(v1.x * nf); d[5] = (short)f2b(v1.y * nf);
            d[6] = (short)f2b(v1.z * nf); d[7] = (short)f2b(v1.w * nf);
        }
        // stage Vc (bf16): 144 rows x 32 groups of 8 floats
        for (int e = tid; e < 4608; e += 1024) {
            int r = e >> 5, j8 = e & 31;
            const float* src = yaT + ((size_t)n * LL + tIdx[cc * CHK + r]) * CHN + j8 * 8;
            float4 v0 = *(const float4*)src, v1 = *(const float4*)(src + 4);
            short* d = &Vs[r * VSTR + j8 * 8];
            d[0] = (short)f2b(v0.x); d[1] = (short)f2b(v0.y); d[2] = (short)f2b(v0.z); d[3] = (short)f2b(v0.w);
            d[4] = (short)f2b(v1.x); d[5] = (short)f2b(v1.y); d[6] = (short)f2b(v1.z); d[7] = (short)f2b(v1.w);
        }
        // zero V pad rows 144..159
        {
            unsigned int* vz = (unsigned int*)Vs;
            for (int e = tid; e < 16 * (VSTR / 2); e += 1024) {
                int r = e / (VSTR / 2), c = e % (VSTR / 2);
                vz[(144 + r) * (VSTR / 2) + c] = 0u;
            }
        }
        __syncthreads();                // (b) staging done

        // preload V B-frags for this wave's e-tile: 5 k-steps
        bf16x8 vfrag[5];
#pragma unroll
        for (int ks = 0; ks < 5; ks++) {
#pragma unroll
            for (int i = 0; i < 8; i++)
                vfrag[ks][i] = Vs[(ks * 32 + lq * 8 + i) * VSTR + et * 16 + lm];
        }

        // QK: tiles (mt,nt) of 144x144 S; wave w takes tt = w, w+16, ...
        int li = 0;
        for (int tt = w; tt < 81; tt += 16, li++) {
            int mt = tt / 9, nt = tt - mt * 9;
            f32x4 c = {0.f, 0.f, 0.f, 0.f};
#pragma unroll
            for (int ks = 0; ks < 2; ks++) {
                bf16x8 a = *(const bf16x8*)&Qs[(mt * 16 + lm) * QSTR + ks * 32 + lq * 8];
                bf16x8 b = *(const bf16x8*)&UN[(nt * 16 + lm) * QSTR + ks * 32 + lq * 8];
                c = __builtin_amdgcn_mfma_f32_16x16x32_bf16(a, b, c, 0, 0, 0);
            }
#pragma unroll
            for (int r = 0; r < 4; r++) {
                int mrow = mt * 16 + lq * 4 + r;
                float ql = 1.0f / nfs[mrow];     // |q| (clamped)
                pbuf[li][r] = __expf(c[r] - ql);
            }
        }
        __syncthreads();                // (c) all K̂c reads done — safe to overwrite UN with P

        // write P (bf16, stride PSTR) + zero pad cols 144..159
        li = 0;
        for (int tt = w; tt < 81; tt += 16, li++) {
            int mt = tt / 9, nt = tt - mt * 9;
#pragma unroll
            for (int r = 0; r < 4; r++)
                UN[(mt * 16 + lq * 4 + r) * PSTR + nt * 16 + lm] = (short)f2b(pbuf[li][r]);
        }
        for (int e = tid; e < 2304; e += 1024) {
            int r = e >> 4, c = 144 + (e & 15);
            UN[r * PSTR + c] = 0;
        }
        __syncthreads();                // (d) P ready

        // lsum partial row sums (288 slots, b128 reads)
        for (int e = tid; e < 288; e += 1024) {
            int r = e >> 1, half = e & 1;
            float s = 0.f;
#pragma unroll
            for (int i = 0; i < 9; i++) {
                bf16x8 v = *(const bf16x8*)&UN[r * PSTR + half * 72 + i * 8];
#pragma unroll
                for (int q2 = 0; q2 < 8; q2++) s += b2f((unsigned short)v[q2]);
            }
            atomicAdd(&lsum[r], s);
        }

        // PV: 9 m-tiles, K=160 (5 k-steps)
#pragma unroll
        for (int mt = 0; mt < 9; mt++) {
            f32x4 c = accO[mt];
#pragma unroll
            for (int ks = 0; ks < 5; ks++) {
                bf16x8 a = *(const bf16x8*)&UN[(mt * 16 + lm) * PSTR + ks * 32 + lq * 8];
                c = __builtin_amdgcn_mfma_f32_16x16x32_bf16(a, vfrag[ks], c, 0, 0, 0);
            }
            accO[mt] = c;
        }
    }

    __syncthreads();                    // (e) last chunk's lsum atomics done
    if (tid < 144) {
        float l = lsum[tid];
        linv[tid] = 1.0f / l;
        float ql = 1.0f / nfs[tid];
        bs[(size_t)n * NJ + (size_t)h * LL + tIdx[tid]] = ql + __logf(l);
    }
    __syncthreads();                    // (f) linv ready

    // write Osort (bf16, sorted space)
#pragma unroll
    for (int mt = 0; mt < 9; mt++) {
        f32x4 c = accO[mt];
#pragma unroll
        for (int r = 0; r < 4; r++) {
            int mrow = mt * 16 + lq * 4 + r;
            float inv = linv[mrow];
            Osort[(sbase + (size_t)k * CHK + mrow) * CHN + et * 16 + lm] = f2b(c[r] * inv);
        }
    }
}

// ---------------------------------------------------------------- softmax over the 4 hashes
__global__ __launch_bounds__(256) void probs_k(const float* __restrict__ bs, float* __restrict__ pr)
{
    int g = blockIdx.x * 256 + threadIdx.x;
    int n = g / LL, t = g % LL;
    const float* b = bs + (size_t)n * NJ;
    float b0 = b[0 * LL + t], b1 = b[1 * LL + t], b2 = b[2 * LL + t], b3 = b[3 * LL + t];
    float mx = fmaxf(fmaxf(b0, b1), fmaxf(b2, b3));
    float e0 = __expf(b0 - mx), e1 = __expf(b1 - mx), e2 = __expf(b2 - mx), e3 = __expf(b3 - mx);
    float inv = 1.f / (e0 + e1 + e2 + e3);
    float* p = pr + (size_t)n * NJ;
    p[0 * LL + t] = e0 * inv;
    p[1 * LL + t] = e1 * inv;
    p[2 * LL + t] = e2 * inv;
    p[3 * LL + t] = e3 * inv;
}

// ---------------------------------------------------------------- fused combine (4 hashes) + transpose + residual
__global__ __launch_bounds__(256) void combfin_k(
    const unsigned short* __restrict__ Osort, const float* __restrict__ pr,
    const int* __restrict__ undo, const float* __restrict__ inp, float* __restrict__ out)
{
    __shared__ float ac[32][260];
    __shared__ int   uS[4][32];
    __shared__ float pS[4][32];
    const int n = blockIdx.y;
    const int t0 = blockIdx.x * 32;    // grid.x = 288
    const int tid = threadIdx.x;
    if (tid < 128) {
        int hh = tid >> 5, tt = tid & 31;
        size_t idx = (size_t)n * NJ + (size_t)hh * LL + t0 + tt;
        uS[hh][tt] = undo[idx];
        pS[hh][tt] = pr[idx];
    }
    __syncthreads();
    const int g = tid & 63, tq = tid >> 6;   // 64 e-quads x 4 t-groups (8 t each)
    for (int tt8 = 0; tt8 < 8; tt8++) {
        int t = tq * 8 + tt8;
        float a0 = 0.f, a1 = 0.f, a2 = 0.f, a3 = 0.f;
#pragma unroll
        for (int hh = 0; hh < 4; hh++) {
            int row = uS[hh][t];
            float p = pS[hh][t];
            const unsigned short* v = &Osort[((size_t)n * NJ + row) * CHN + g * 4];
            ushort4 u = *(const ushort4*)v;
            a0 = fmaf(p, b2f(u.x), a0);
            a1 = fmaf(p, b2f(u.y), a1);
            a2 = fmaf(p, b2f(u.z), a2);
            a3 = fmaf(p, b2f(u.w), a3);
        }
        float4 o = make_float4(a0, a1, a2, a3);
        *(float4*)&ac[t][g * 4] = o;
    }
    __syncthreads();
    const int tp = tid & 31, er = tid >> 5;
    const float* inN = inp + (size_t)n * LL * CHN;
    float* outN = out + (size_t)n * LL * CHN;
    for (int it = 0; it < 32; it++) {
        int e = er + it * 8;
        size_t o = (size_t)e * LL + t0 + tp;
        outN[o] = ac[tp][e] * 0.1f + inN[o];
    }
}

// ---------------------------------------------------------------- launch
extern "C" void kernel_launch(void* const* d_in, const int* in_sizes, int n_in,
                              void* d_out, int out_size, void* d_ws, size_t ws_size,
                              hipStream_t stream)
{
    (void)in_sizes; (void)n_in; (void)out_size; (void)ws_size;
    const float* input   = (const float*)d_in[0];
    const float* w_match = (const float*)d_in[1];
    const float* b_match = (const float*)d_in[2];
    const float* w_asm   = (const float*)d_in[3];
    const float* b_asm   = (const float*)d_in[4];
    const float* rot     = (const float*)d_in[5];
    float* out = (float*)d_out;

    char* ws = (char*)d_ws;
    size_t off = 0;
    auto alloc = [&](size_t bytes) -> void* {
        void* p = ws + off;
        off += (bytes + 255) & ~(size_t)255;
        return p;
    };
    float* ya    = (float*)alloc((size_t)NB * LL * CHN * 4);
    float* yaT   = (float*)alloc((size_t)NB * LL * CHN * 4);
    float* xm    = (float*)alloc((size_t)NB * LL * CC * 4);
    float* xmT   = (float*)alloc((size_t)NB * LL * CC * 4);
    float* ssq   = (float*)alloc((size_t)NB * LL * 4);
    int*   codes = (int*)  alloc((size_t)NB * NJ * 4);
    int*   rank  = (int*)  alloc((size_t)NB * NJ * 4);
    int*   hist  = (int*)  alloc((size_t)NB * NJ * 4);
    int*   sidx  = (int*)  alloc((size_t)NB * NJ * 4);
    int*   undo  = (int*)  alloc((size_t)NB * NJ * 4);
    float* bs    = (float*)alloc((size_t)NB * NJ * 4);
    float* pr    = (float*)alloc((size_t)NB * NJ * 4);
    unsigned short* Osort = (unsigned short*)alloc((size_t)NB * NJ * CHN * 2);

    conv3x3_k<<<dim3(144, 1, NB), 256, 0, stream>>>(input, w_match, b_match, xm, CC);
    conv3x3_k<<<dim3(144, 4, NB), 256, 0, stream>>>(input, w_asm, b_asm, ya, CHN);
    transpose_k<<<dim3(288, 2, NB), 256, 0, stream>>>(xm, xmT, CC, LL);
    transpose_k<<<dim3(288, 8, NB), 256, 0, stream>>>(ya, yaT, CHN, LL);
    hash_k<<<dim3(144), 256, 0, stream>>>(xmT, rot, codes, ssq);
    sort_hist_k<<<dim3(144, NB), 256, 0, stream>>>(codes, hist, rank);
    sort_scan_k<<<dim3(NB), 256, 0, stream>>>(hist);
    sort_scatter_k<<<dim3(144, NB), 256, 0, stream>>>(codes, rank, hist, sidx, undo);
    attn_mfma_k<<<dim3(NCHUNK, NHASH, NB), 1024, 0, stream>>>(xmT, yaT, ssq, sidx, Osort, bs);
    probs_k<<<dim3(144), 256, 0, stream>>>(bs, pr);
    combfin_k<<<dim3(288, NB), 256, 0, stream>>>(Osort, pr, undo, input, out);
}

// Round 4
// 713.378 us; speedup vs baseline: 6.1117x; 1.6988x over previous
//
#include <hip/hip_runtime.h>
#include <cstdint>
#include <cstddef>

#define NB 4
#define HH 96
#define WW 96
#define CHN 256
#define CC 64
#define LL 9216
#define NHASH 4
#define HBK 64
#define CHK 144
#define NCHUNK 64
#define NJ 36864   // NHASH * LL

typedef __attribute__((ext_vector_type(8))) short bf16x8;
typedef __attribute__((ext_vector_type(8))) unsigned short u16x8;
typedef __attribute__((ext_vector_type(4))) float f32x4;

__device__ __forceinline__ unsigned short f2b(float f) {
    unsigned int x = __float_as_uint(f);
    x += 0x7FFFu + ((x >> 16) & 1u);
    return (unsigned short)(x >> 16);
}
__device__ __forceinline__ float b2f(unsigned short u) {
    return __uint_as_float(((unsigned int)u) << 16);
}

// ---------------------------------------------------------------- conv 3x3 SAME (fp32 — match path, feeds hashing)
__global__ __launch_bounds__(256) void conv3x3_k(
    const float* __restrict__ in, const float* __restrict__ wgt,
    const float* __restrict__ bias, float* __restrict__ out, int CO)
{
    __shared__ float inb[64][36];
    __shared__ float wb[32][68];
    const int n = blockIdx.z;
    const int p0 = blockIdx.x * 64;
    const int co0 = blockIdx.y * 64;
    const int tid = threadIdx.x;
    const int cg = tid & 15;
    const int pg = tid >> 4;
    float acc[4][4];
#pragma unroll
    for (int a = 0; a < 4; a++)
#pragma unroll
        for (int b = 0; b < 4; b++) acc[a][b] = 0.f;
    const float* inN = in + (size_t)n * LL * CHN;
    for (int ky = 0; ky < 3; ky++)
    for (int kx = 0; kx < 3; kx++) {
        for (int ci0 = 0; ci0 < CHN; ci0 += 32) {
#pragma unroll
            for (int ld = 0; ld < 2; ld++) {
                int lin = tid * 2 + ld;
                int px = lin >> 3;
                int c4 = (lin & 7) * 4;
                int p = p0 + px;
                int hh = p / WW + ky - 1;
                int ww2 = p % WW + kx - 1;
                float4 v = make_float4(0.f, 0.f, 0.f, 0.f);
                if (hh >= 0 && hh < HH && ww2 >= 0 && ww2 < WW)
                    v = *(const float4*)(inN + (size_t)(hh * WW + ww2) * CHN + ci0 + c4);
                *(float4*)&inb[px][c4] = v;
            }
#pragma unroll
            for (int ld = 0; ld < 2; ld++) {
                int lin = tid * 2 + ld;
                int ci = lin >> 4;
                int c4 = (lin & 15) * 4;
                float4 v = *(const float4*)(wgt + (size_t)((ky * 3 + kx) * CHN + ci0 + ci) * CO + co0 + c4);
                *(float4*)&wb[ci][c4] = v;
            }
            __syncthreads();
#pragma unroll
            for (int s = 0; s < 8; s++) {
                int ci = s * 4;
                float4 bv0 = *(float4*)&wb[ci + 0][cg * 4];
                float4 bv1 = *(float4*)&wb[ci + 1][cg * 4];
                float4 bv2 = *(float4*)&wb[ci + 2][cg * 4];
                float4 bv3 = *(float4*)&wb[ci + 3][cg * 4];
#pragma unroll
                for (int k = 0; k < 4; k++) {
                    float4 av = *(float4*)&inb[pg * 4 + k][ci];
                    acc[k][0] = fmaf(av.x, bv0.x, fmaf(av.y, bv1.x, fmaf(av.z, bv2.x, fmaf(av.w, bv3.x, acc[k][0]))));
                    acc[k][1] = fmaf(av.x, bv0.y, fmaf(av.y, bv1.y, fmaf(av.z, bv2.y, fmaf(av.w, bv3.y, acc[k][1]))));
                    acc[k][2] = fmaf(av.x, bv0.z, fmaf(av.y, bv1.z, fmaf(av.z, bv2.z, fmaf(av.w, bv3.z, acc[k][2]))));
                    acc[k][3] = fmaf(av.x, bv0.w, fmaf(av.y, bv1.w, fmaf(av.z, bv2.w, fmaf(av.w, bv3.w, acc[k][3]))));
                }
            }
            __syncthreads();
        }
    }
    float* outN = out + (size_t)n * LL * CO;
#pragma unroll
    for (int k = 0; k < 4; k++) {
        int p = p0 + pg * 4 + k;
        float4 o;
        o.x = acc[k][0] + bias[co0 + cg * 4 + 0];
        o.y = acc[k][1] + bias[co0 + cg * 4 + 1];
        o.z = acc[k][2] + bias[co0 + cg * 4 + 2];
        o.w = acc[k][3] + bias[co0 + cg * 4 + 3];
        *(float4*)(outN + (size_t)p * CO + co0 + cg * 4) = o;
    }
}

// ---------------------------------------------------------------- fp32 transpose (match embedding)
__global__ __launch_bounds__(256) void transpose_k(const float* __restrict__ in, float* __restrict__ out,
                                                   int R, int Cc)
{
    __shared__ float tl[32][33];
    const int n = blockIdx.z;
    const size_t base = (size_t)n * R * Cc;
    int c0 = blockIdx.x * 32, r0 = blockIdx.y * 32;
    int tx = threadIdx.x & 31, ty0 = threadIdx.x >> 5;
#pragma unroll
    for (int i = 0; i < 32; i += 8)
        tl[ty0 + i][tx] = in[base + (size_t)(r0 + ty0 + i) * Cc + c0 + tx];
    __syncthreads();
#pragma unroll
    for (int i = 0; i < 32; i += 8)
        out[base + (size_t)(c0 + ty0 + i) * R + r0 + tx] = tl[tx][ty0 + i];
}

// ---------------------------------------------------------------- input fp32 -> bf16
__global__ __launch_bounds__(256) void cvt_in_k(const float* __restrict__ in, unsigned short* __restrict__ out)
{
    size_t g = ((size_t)blockIdx.x * 256 + threadIdx.x) * 8;   // grid exact: total/2048
    float4 v0 = *(const float4*)(in + g);
    float4 v1 = *(const float4*)(in + g + 4);
    u16x8 o;
    o[0] = f2b(v0.x); o[1] = f2b(v0.y); o[2] = f2b(v0.z); o[3] = f2b(v0.w);
    o[4] = f2b(v1.x); o[5] = f2b(v1.y); o[6] = f2b(v1.z); o[7] = f2b(v1.w);
    *(u16x8*)(out + g) = o;
}

// ---------------------------------------------------------------- w_asm [tap][ci][co] fp32 -> wT [tap][co][ci] bf16
__global__ __launch_bounds__(256) void cvt_wT_k(const float* __restrict__ w, unsigned short* __restrict__ wT)
{
    __shared__ float tl[32][33];
    const int tap = blockIdx.z;
    const int c0 = blockIdx.x * 32;   // ci
    const int o0 = blockIdx.y * 32;   // co
    const int tx = threadIdx.x & 31, ty0 = threadIdx.x >> 5;  // ty0 0..7
#pragma unroll
    for (int i = 0; i < 32; i += 8)
        tl[ty0 + i][tx] = w[((size_t)tap * 256 + c0 + ty0 + i) * 256 + o0 + tx];
    __syncthreads();
#pragma unroll
    for (int i = 0; i < 32; i += 8)
        wT[((size_t)tap * 256 + o0 + ty0 + i) * 256 + c0 + tx] = f2b(tl[tx][ty0 + i]);
}

// ---------------------------------------------------------------- MFMA conv 3x3 (value path, bf16)
// block: 128 pixels x 128 couts; 256 threads = 4 waves (2x2 of 64x64)
__global__ __launch_bounds__(256) void conv_mfma_k(
    const unsigned short* __restrict__ in_bf, const unsigned short* __restrict__ wT,
    const float* __restrict__ bias, unsigned short* __restrict__ ya_bf)
{
    __shared__ short As[128 * 32];
    __shared__ short Bs[128 * 32];
    const int n = blockIdx.z, p0 = blockIdx.x * 128, co0 = blockIdx.y * 128;
    const int tid = threadIdx.x;
    const int w = tid >> 6, wr = w >> 1, wc = w & 1;
    const int lane = tid & 63, lm = lane & 15, lq = lane >> 4;
    const int r = tid >> 1, hf = tid & 1;          // staging row 0..127, 16-elem half
    const int p = p0 + r, py = p / WW, px = p % WW;
    const unsigned short* inN = in_bf + (size_t)n * LL * CHN;

    f32x4 acc[4][4];
#pragma unroll
    for (int a = 0; a < 4; a++)
#pragma unroll
        for (int b = 0; b < 4; b++) acc[a][b] = (f32x4){0.f, 0.f, 0.f, 0.f};

    for (int tap = 0; tap < 9; tap++) {
        const int ky = tap / 3, kx = tap - ky * 3;
        const int sy = py + ky - 1, sx = px + kx - 1;
        const bool valid = ((unsigned)sy < HH) && ((unsigned)sx < WW);
        const unsigned short* asrc = inN + (size_t)(sy * WW + sx) * CHN + hf * 16;
        const unsigned short* bsrc = wT + ((size_t)tap * 256 + co0 + r) * 256 + hf * 16;
        for (int ci0 = 0; ci0 < 256; ci0 += 32) {
            u16x8 av0 = (u16x8){0,0,0,0,0,0,0,0}, av1 = (u16x8){0,0,0,0,0,0,0,0};
            if (valid) {
                av0 = *(const u16x8*)(asrc + ci0);
                av1 = *(const u16x8*)(asrc + ci0 + 8);
            }
            u16x8 bv0 = *(const u16x8*)(bsrc + ci0);
            u16x8 bv1 = *(const u16x8*)(bsrc + ci0 + 8);
            __syncthreads();   // prior k-step's LDS reads done
            *(u16x8*)&As[r * 32 + hf * 16]     = av0;
            *(u16x8*)&As[r * 32 + hf * 16 + 8] = av1;
            *(u16x8*)&Bs[r * 32 + hf * 16]     = bv0;
            *(u16x8*)&Bs[r * 32 + hf * 16 + 8] = bv1;
            __syncthreads();
            bf16x8 af[4], bf[4];
#pragma unroll
            for (int mt = 0; mt < 4; mt++)
                af[mt] = *(const bf16x8*)&As[(wr * 64 + mt * 16 + lm) * 32 + lq * 8];
#pragma unroll
            for (int nt = 0; nt < 4; nt++)
                bf[nt] = *(const bf16x8*)&Bs[(wc * 64 + nt * 16 + lm) * 32 + lq * 8];
#pragma unroll
            for (int mt = 0; mt < 4; mt++)
#pragma unroll
                for (int nt = 0; nt < 4; nt++)
                    acc[mt][nt] = __builtin_amdgcn_mfma_f32_16x16x32_bf16(af[mt], bf[nt], acc[mt][nt], 0, 0, 0);
        }
    }
    // epilogue: bias + bf16 store (C map: row = lq*4+r4, col = lm)
    float bv[4];
#pragma unroll
    for (int nt = 0; nt < 4; nt++) bv[nt] = bias[co0 + wc * 64 + nt * 16 + lm];
#pragma unroll
    for (int mt = 0; mt < 4; mt++) {
#pragma unroll
        for (int r4 = 0; r4 < 4; r4++) {
            int row = p0 + wr * 64 + mt * 16 + lq * 4 + r4;
            unsigned short* od = ya_bf + ((size_t)n * LL + row) * CHN + co0 + wc * 64;
#pragma unroll
            for (int nt = 0; nt < 4; nt++)
                od[nt * 16 + lm] = f2b(acc[mt][nt][r4] + bv[nt]);
        }
    }
}

// ---------------------------------------------------------------- bf16 transpose: ya_bf (viewed [256][9216]) -> yaT [9216][256]
__global__ __launch_bounds__(256) void transpose_bf_k(const unsigned short* __restrict__ in,
                                                      unsigned short* __restrict__ out)
{
    __shared__ unsigned short tl[64][65];
    const int n = blockIdx.z;
    const size_t base = (size_t)n * LL * CHN;
    const int t0 = blockIdx.x * 64, e0 = blockIdx.y * 64;
    const int tx = threadIdx.x & 63, ty0 = threadIdx.x >> 6;   // ty0 0..3
#pragma unroll
    for (int i = 0; i < 16; i++) {
        int row = ty0 + i * 4;
        tl[row][tx] = in[base + (size_t)(e0 + row) * LL + t0 + tx];
    }
    __syncthreads();
#pragma unroll
    for (int i = 0; i < 16; i++) {
        int row = ty0 + i * 4;
        out[base + (size_t)(t0 + row) * CHN + e0 + tx] = tl[tx][row];
    }
}

// ---------------------------------------------------------------- hashing: codes + squared norms (fp32!)
__global__ __launch_bounds__(256) void hash_k(const float* __restrict__ xmT, const float* __restrict__ rot,
                                              int* __restrict__ codes, float* __restrict__ ssq)
{
    __shared__ float rs[8192];  // rotations: (64, 4, 32)
    for (int e = threadIdx.x; e < 8192; e += 256) rs[e] = rot[e];
    __syncthreads();
    int g = blockIdx.x * 256 + threadIdx.x;   // grid exact: NB*LL
    int n = g / LL, t = g % LL;
    float x[64];
    const float* src = xmT + (size_t)g * CC;
#pragma unroll
    for (int f4 = 0; f4 < 16; f4++) {
        float4 v = *(const float4*)(src + f4 * 4);
        x[f4 * 4 + 0] = v.x; x[f4 * 4 + 1] = v.y; x[f4 * 4 + 2] = v.z; x[f4 * 4 + 3] = v.w;
    }
    float ss = 0.f;
#pragma unroll
    for (int f = 0; f < 64; f++) ss += x[f] * x[f];
    ssq[g] = ss;
    for (int h = 0; h < NHASH; h++) {
        float bp = -1e30f, bn = -1e30f;
        int ip = 0, inn = 0;
        for (int i = 0; i < 32; i++) {
            float d = 0.f;
#pragma unroll
            for (int f = 0; f < 64; f++) d = fmaf(x[f], rs[f * 128 + h * 32 + i], d);
            if (d > bp) { bp = d; ip = i; }
            if (-d > bn) { bn = -d; inn = i; }
        }
        int code = (bp >= bn) ? ip : (32 + inn);
        codes[(size_t)n * NJ + h * LL + t] = code + h * HBK;
    }
}

// ---------------------------------------------------------------- stable counting sort (256 buckets)
__global__ __launch_bounds__(256) void sort_hist_k(const int* __restrict__ codes, int* __restrict__ hist,
                                                   int* __restrict__ rank)
{
    __shared__ int lc[256];
    __shared__ int lh[256];
    const int n = blockIdx.y, seg = blockIdx.x, tid = threadIdx.x;
    int j = seg * 256 + tid;
    int c = codes[(size_t)n * NJ + j];
    lc[tid] = c;
    lh[tid] = 0;
    __syncthreads();
    int r = 0;
    for (int q = 0; q < tid; q++) r += (lc[q] == c) ? 1 : 0;
    atomicAdd(&lh[c], 1);
    __syncthreads();
    rank[(size_t)n * NJ + j] = r;
    hist[(size_t)n * NJ + tid * 144 + seg] = lh[tid];
}

__global__ __launch_bounds__(256) void sort_scan_k(int* __restrict__ hist)
{
    const int n = blockIdx.x;
    const int key = threadIdx.x;
    int* hn = hist + (size_t)n * NJ;
    int sum = 0;
    for (int s = 0; s < 144; s++) sum += hn[key * 144 + s];
    __shared__ int tot[256];
    tot[key] = sum;
    __syncthreads();
    int excl = 0;
    for (int q = 0; q < key; q++) excl += tot[q];
    int run = excl;
    for (int s = 0; s < 144; s++) { int v = hn[key * 144 + s]; hn[key * 144 + s] = run; run += v; }
}

__global__ __launch_bounds__(256) void sort_scatter_k(const int* __restrict__ codes, const int* __restrict__ rank,
                                                      const int* __restrict__ hist, int* __restrict__ sidx,
                                                      int* __restrict__ undo)
{
    const int n = blockIdx.y, seg = blockIdx.x, tid = threadIdx.x;
    int j = seg * 256 + tid;
    int c = codes[(size_t)n * NJ + j];
    int dest = hist[(size_t)n * NJ + c * 144 + seg] + rank[(size_t)n * NJ + j];
    sidx[(size_t)n * NJ + dest] = j;
    undo[(size_t)n * NJ + j] = dest;
}

// ---------------------------------------------------------------- MFMA attention (V now bf16 input)
#define QSTR 72     // Q/K row stride in shorts (144B)
#define PSTR 168    // P row stride in shorts (336B)
#define VSTR 264    // V row stride in shorts (528B)
__global__ __launch_bounds__(1024) void attn_mfma_k(
    const float* __restrict__ xmT, const unsigned short* __restrict__ yaT,
    const float* __restrict__ ssq, const int* __restrict__ sidx,
    unsigned short* __restrict__ Osort, float* __restrict__ bs)
{
    __shared__ short Qs[144 * QSTR];
    __shared__ short UN[144 * PSTR];    // K̂c (stride QSTR) then, after sync, P (stride PSTR)
    __shared__ short Vs[160 * VSTR];
    __shared__ int   tIdx[432];
    __shared__ float nfs[432];
    __shared__ float lsum[144];
    __shared__ float linv[144];

    const int k = blockIdx.x, h = blockIdx.y, n = blockIdx.z;
    const int tid = threadIdx.x;
    const int w = tid >> 6;
    const int lane = tid & 63;
    const int lm = lane & 15, lq = lane >> 4;
    const size_t sbase = (size_t)n * NJ + (size_t)h * LL;

    if (tid < 432) {
        int cc = tid / CHK, rr = tid - cc * CHK;
        int c = (cc == 0) ? k : (cc == 1 ? (k + NCHUNK - 1) & (NCHUNK - 1) : (k + 1) & (NCHUNK - 1));
        int j = sidx[sbase + c * CHK + rr];
        int t = j % LL;
        tIdx[tid] = t;
        nfs[tid] = rsqrtf(fmaxf(ssq[(size_t)n * LL + t], 5e-5f));
    }
    if (tid < 144) lsum[tid] = 0.f;
    __syncthreads();

    for (int e = tid; e < 1152; e += 1024) {
        int r = e >> 3, j8 = e & 7;
        const float* src = xmT + ((size_t)n * LL + tIdx[r]) * CC + j8 * 8;
        float4 v0 = *(const float4*)src, v1 = *(const float4*)(src + 4);
        short* d = &Qs[r * QSTR + j8 * 8];
        d[0] = (short)f2b(v0.x); d[1] = (short)f2b(v0.y); d[2] = (short)f2b(v0.z); d[3] = (short)f2b(v0.w);
        d[4] = (short)f2b(v1.x); d[5] = (short)f2b(v1.y); d[6] = (short)f2b(v1.z); d[7] = (short)f2b(v1.w);
    }

    const int et = w;
    f32x4 accO[9];
#pragma unroll
    for (int mt = 0; mt < 9; mt++) accO[mt] = (f32x4){0.f, 0.f, 0.f, 0.f};
    float pbuf[6][4];

    for (int cc = 0; cc < 3; cc++) {
        __syncthreads();
        for (int e = tid; e < 1152; e += 1024) {
            int r = e >> 3, j8 = e & 7;
            const float* src = xmT + ((size_t)n * LL + tIdx[cc * CHK + r]) * CC + j8 * 8;
            float nf = nfs[cc * CHK + r];
            float4 v0 = *(const float4*)src, v1 = *(const float4*)(src + 4);
            short* d = &UN[r * QSTR + j8 * 8];
            d[0] = (short)f2b(v0.x * nf); d[1] = (short)f2b(v0.y * nf);
            d[2] = (short)f2b(v0.z * nf); d[3] = (short)f2b(v0.w * nf);
            d[4] = (short)f2b(v1.x * nf); d[5] = (short)f2b(v1.y * nf);
            d[6] = (short)f2b(v1.z * nf); d[7] = (short)f2b(v1.w * nf);
        }
        // stage Vc: raw bf16 copy, 16B per op
        for (int e = tid; e < 4608; e += 1024) {
            int r = e >> 5, j8 = e & 31;
            u16x8 v = *(const u16x8*)(yaT + ((size_t)n * LL + tIdx[cc * CHK + r]) * CHN + j8 * 8);
            *(u16x8*)&Vs[r * VSTR + j8 * 8] = v;
        }
        {
            unsigned int* vz = (unsigned int*)Vs;
            for (int e = tid; e < 16 * (VSTR / 2); e += 1024) {
                int r = e / (VSTR / 2), c = e % (VSTR / 2);
                vz[(144 + r) * (VSTR / 2) + c] = 0u;
            }
        }
        __syncthreads();

        bf16x8 vfrag[5];
#pragma unroll
        for (int ks = 0; ks < 5; ks++) {
#pragma unroll
            for (int i = 0; i < 8; i++)
                vfrag[ks][i] = Vs[(ks * 32 + lq * 8 + i) * VSTR + et * 16 + lm];
        }

        int li = 0;
        for (int tt = w; tt < 81; tt += 16, li++) {
            int mt = tt / 9, nt = tt - mt * 9;
            f32x4 c = {0.f, 0.f, 0.f, 0.f};
#pragma unroll
            for (int ks = 0; ks < 2; ks++) {
                bf16x8 a = *(const bf16x8*)&Qs[(mt * 16 + lm) * QSTR + ks * 32 + lq * 8];
                bf16x8 b = *(const bf16x8*)&UN[(nt * 16 + lm) * QSTR + ks * 32 + lq * 8];
                c = __builtin_amdgcn_mfma_f32_16x16x32_bf16(a, b, c, 0, 0, 0);
            }
#pragma unroll
            for (int r = 0; r < 4; r++) {
                int mrow = mt * 16 + lq * 4 + r;
                float ql = 1.0f / nfs[mrow];
                pbuf[li][r] = __expf(c[r] - ql);
            }
        }
        __syncthreads();

        li = 0;
        for (int tt = w; tt < 81; tt += 16, li++) {
            int mt = tt / 9, nt = tt - mt * 9;
#pragma unroll
            for (int r = 0; r < 4; r++)
                UN[(mt * 16 + lq * 4 + r) * PSTR + nt * 16 + lm] = (short)f2b(pbuf[li][r]);
        }
        for (int e = tid; e < 2304; e += 1024) {
            int r = e >> 4, c = 144 + (e & 15);
            UN[r * PSTR + c] = 0;
        }
        __syncthreads();

        for (int e = tid; e < 288; e += 1024) {
            int r = e >> 1, half = e & 1;
            float s = 0.f;
#pragma unroll
            for (int i = 0; i < 9; i++) {
                bf16x8 v = *(const bf16x8*)&UN[r * PSTR + half * 72 + i * 8];
#pragma unroll
                for (int q2 = 0; q2 < 8; q2++) s += b2f((unsigned short)v[q2]);
            }
            atomicAdd(&lsum[r], s);
        }

#pragma unroll
        for (int mt = 0; mt < 9; mt++) {
            f32x4 c = accO[mt];
#pragma unroll
            for (int ks = 0; ks < 5; ks++) {
                bf16x8 a = *(const bf16x8*)&UN[(mt * 16 + lm) * PSTR + ks * 32 + lq * 8];
                c = __builtin_amdgcn_mfma_f32_16x16x32_bf16(a, vfrag[ks], c, 0, 0, 0);
            }
            accO[mt] = c;
        }
    }

    __syncthreads();
    if (tid < 144) {
        float l = lsum[tid];
        linv[tid] = 1.0f / l;
        float ql = 1.0f / nfs[tid];
        bs[(size_t)n * NJ + (size_t)h * LL + tIdx[tid]] = ql + __logf(l);
    }
    __syncthreads();

#pragma unroll
    for (int mt = 0; mt < 9; mt++) {
        f32x4 c = accO[mt];
#pragma unroll
        for (int r = 0; r < 4; r++) {
            int mrow = mt * 16 + lq * 4 + r;
            float inv = linv[mrow];
            Osort[(sbase + (size_t)k * CHK + mrow) * CHN + et * 16 + lm] = f2b(c[r] * inv);
        }
    }
}

// ---------------------------------------------------------------- softmax over the 4 hashes
__global__ __launch_bounds__(256) void probs_k(const float* __restrict__ bs, float* __restrict__ pr)
{
    int g = blockIdx.x * 256 + threadIdx.x;
    int n = g / LL, t = g % LL;
    const float* b = bs + (size_t)n * NJ;
    float b0 = b[0 * LL + t], b1 = b[1 * LL + t], b2 = b[2 * LL + t], b3 = b[3 * LL + t];
    float mx = fmaxf(fmaxf(b0, b1), fmaxf(b2, b3));
    float e0 = __expf(b0 - mx), e1 = __expf(b1 - mx), e2 = __expf(b2 - mx), e3 = __expf(b3 - mx);
    float inv = 1.f / (e0 + e1 + e2 + e3);
    float* p = pr + (size_t)n * NJ;
    p[0 * LL + t] = e0 * inv;
    p[1 * LL + t] = e1 * inv;
    p[2 * LL + t] = e2 * inv;
    p[3 * LL + t] = e3 * inv;
}

// ---------------------------------------------------------------- fused combine (4 hashes) + transpose + residual
__global__ __launch_bounds__(256) void combfin_k(
    const unsigned short* __restrict__ Osort, const float* __restrict__ pr,
    const int* __restrict__ undo, const float* __restrict__ inp, float* __restrict__ out)
{
    __shared__ float ac[32][260];
    __shared__ int   uS[4][32];
    __shared__ float pS[4][32];
    const int n = blockIdx.y;
    const int t0 = blockIdx.x * 32;
    const int tid = threadIdx.x;
    if (tid < 128) {
        int hh = tid >> 5, tt = tid & 31;
        size_t idx = (size_t)n * NJ + (size_t)hh * LL + t0 + tt;
        uS[hh][tt] = undo[idx];
        pS[hh][tt] = pr[idx];
    }
    __syncthreads();
    const int g = tid & 63, tq = tid >> 6;
    for (int tt8 = 0; tt8 < 8; tt8++) {
        int t = tq * 8 + tt8;
        float a0 = 0.f, a1 = 0.f, a2 = 0.f, a3 = 0.f;
#pragma unroll
        for (int hh = 0; hh < 4; hh++) {
            int row = uS[hh][t];
            float p = pS[hh][t];
            const unsigned short* v = &Osort[((size_t)n * NJ + row) * CHN + g * 4];
            ushort4 u = *(const ushort4*)v;
            a0 = fmaf(p, b2f(u.x), a0);
            a1 = fmaf(p, b2f(u.y), a1);
            a2 = fmaf(p, b2f(u.z), a2);
            a3 = fmaf(p, b2f(u.w), a3);
        }
        float4 o = make_float4(a0, a1, a2, a3);
        *(float4*)&ac[t][g * 4] = o;
    }
    __syncthreads();
    const int tp = tid & 31, er = tid >> 5;
    const float* inN = inp + (size_t)n * LL * CHN;
    float* outN = out + (size_t)n * LL * CHN;
    for (int it = 0; it < 32; it++) {
        int e = er + it * 8;
        size_t o = (size_t)e * LL + t0 + tp;
        outN[o] = ac[tp][e] * 0.1f + inN[o];
    }
}

// ---------------------------------------------------------------- launch
extern "C" void kernel_launch(void* const* d_in, const int* in_sizes, int n_in,
                              void* d_out, int out_size, void* d_ws, size_t ws_size,
                              hipStream_t stream)
{
    (void)in_sizes; (void)n_in; (void)out_size; (void)ws_size;
    const float* input   = (const float*)d_in[0];
    const float* w_match = (const float*)d_in[1];
    const float* b_match = (const float*)d_in[2];
    const float* w_asm   = (const float*)d_in[3];
    const float* b_asm   = (const float*)d_in[4];
    const float* rot     = (const float*)d_in[5];
    float* out = (float*)d_out;

    char* ws = (char*)d_ws;
    size_t off = 0;
    auto alloc = [&](size_t bytes) -> void* {
        void* p = ws + off;
        off += (bytes + 255) & ~(size_t)255;
        return p;
    };
    unsigned short* in_bf = (unsigned short*)alloc((size_t)NB * LL * CHN * 2);
    unsigned short* wT_bf = (unsigned short*)alloc((size_t)9 * CHN * CHN * 2);
    unsigned short* ya_bf = (unsigned short*)alloc((size_t)NB * LL * CHN * 2);
    unsigned short* yaT   = (unsigned short*)alloc((size_t)NB * LL * CHN * 2);
    float* xm    = (float*)alloc((size_t)NB * LL * CC * 4);
    float* xmT   = (float*)alloc((size_t)NB * LL * CC * 4);
    float* ssq   = (float*)alloc((size_t)NB * LL * 4);
    int*   codes = (int*)  alloc((size_t)NB * NJ * 4);
    int*   rank  = (int*)  alloc((size_t)NB * NJ * 4);
    int*   hist  = (int*)  alloc((size_t)NB * NJ * 4);
    int*   sidx  = (int*)  alloc((size_t)NB * NJ * 4);
    int*   undo  = (int*)  alloc((size_t)NB * NJ * 4);
    float* bs    = (float*)alloc((size_t)NB * NJ * 4);
    float* pr    = (float*)alloc((size_t)NB * NJ * 4);
    unsigned short* Osort = (unsigned short*)alloc((size_t)NB * NJ * CHN * 2);

    // match path (fp32 — feeds hashing)
    conv3x3_k<<<dim3(144, 1, NB), 256, 0, stream>>>(input, w_match, b_match, xm, CC);
    transpose_k<<<dim3(288, 2, NB), 256, 0, stream>>>(xm, xmT, CC, LL);
    // value path (bf16 MFMA)
    cvt_in_k<<<dim3(4608), 256, 0, stream>>>(input, in_bf);
    cvt_wT_k<<<dim3(8, 8, 9), 256, 0, stream>>>(w_asm, wT_bf);
    conv_mfma_k<<<dim3(72, 2, NB), 256, 0, stream>>>(in_bf, wT_bf, b_asm, ya_bf);
    transpose_bf_k<<<dim3(144, 4, NB), 256, 0, stream>>>(ya_bf, yaT);
    // hashing + sort
    hash_k<<<dim3(144), 256, 0, stream>>>(xmT, rot, codes, ssq);
    sort_hist_k<<<dim3(144, NB), 256, 0, stream>>>(codes, hist, rank);
    sort_scan_k<<<dim3(NB), 256, 0, stream>>>(hist);
    sort_scatter_k<<<dim3(144, NB), 256, 0, stream>>>(codes, rank, hist, sidx, undo);
    // attention + combine
    attn_mfma_k<<<dim3(NCHUNK, NHASH, NB), 1024, 0, stream>>>(xmT, yaT, ssq, sidx, Osort, bs);
    probs_k<<<dim3(144), 256, 0, stream>>>(bs, pr);
    combfin_k<<<dim3(288, NB), 256, 0, stream>>>(Osort, pr, undo, input, out);
}

// Round 6
// 699.780 us; speedup vs baseline: 6.2304x; 1.0194x over previous
//
#include <hip/hip_runtime.h>
#include <cstdint>
#include <cstddef>

#define NB 4
#define HH 96
#define WW 96
#define CHN 256
#define CC 64
#define LL 9216
#define NHASH 4
#define HBK 64
#define CHK 144
#define NCHUNK 64
#define NJ 36864   // NHASH * LL

typedef __attribute__((ext_vector_type(8))) short bf16x8;
typedef __attribute__((ext_vector_type(8))) unsigned short u16x8;
typedef __attribute__((ext_vector_type(4))) float f32x4;

__device__ __forceinline__ unsigned short f2b(float f) {
    unsigned int x = __float_as_uint(f);
    x += 0x7FFFu + ((x >> 16) & 1u);
    return (unsigned short)(x >> 16);
}
__device__ __forceinline__ float b2f(unsigned short u) {
    return __uint_as_float(((unsigned int)u) << 16);
}

// ---------------------------------------------------------------- conv 3x3 SAME (fp32 — match path, feeds hashing)
__global__ __launch_bounds__(256) void conv3x3_k(
    const float* __restrict__ in, const float* __restrict__ wgt,
    const float* __restrict__ bias, float* __restrict__ out, int CO)
{
    __shared__ float inb[64][36];
    __shared__ float wb[32][68];
    const int n = blockIdx.z;
    const int p0 = blockIdx.x * 64;
    const int co0 = blockIdx.y * 64;
    const int tid = threadIdx.x;
    const int cg = tid & 15;
    const int pg = tid >> 4;
    float acc[4][4];
#pragma unroll
    for (int a = 0; a < 4; a++)
#pragma unroll
        for (int b = 0; b < 4; b++) acc[a][b] = 0.f;
    const float* inN = in + (size_t)n * LL * CHN;
    for (int ky = 0; ky < 3; ky++)
    for (int kx = 0; kx < 3; kx++) {
        for (int ci0 = 0; ci0 < CHN; ci0 += 32) {
#pragma unroll
            for (int ld = 0; ld < 2; ld++) {
                int lin = tid * 2 + ld;
                int px = lin >> 3;
                int c4 = (lin & 7) * 4;
                int p = p0 + px;
                int hh = p / WW + ky - 1;
                int ww2 = p % WW + kx - 1;
                float4 v = make_float4(0.f, 0.f, 0.f, 0.f);
                if (hh >= 0 && hh < HH && ww2 >= 0 && ww2 < WW)
                    v = *(const float4*)(inN + (size_t)(hh * WW + ww2) * CHN + ci0 + c4);
                *(float4*)&inb[px][c4] = v;
            }
#pragma unroll
            for (int ld = 0; ld < 2; ld++) {
                int lin = tid * 2 + ld;
                int ci = lin >> 4;
                int c4 = (lin & 15) * 4;
                float4 v = *(const float4*)(wgt + (size_t)((ky * 3 + kx) * CHN + ci0 + ci) * CO + co0 + c4);
                *(float4*)&wb[ci][c4] = v;
            }
            __syncthreads();
#pragma unroll
            for (int s = 0; s < 8; s++) {
                int ci = s * 4;
                float4 bv0 = *(float4*)&wb[ci + 0][cg * 4];
                float4 bv1 = *(float4*)&wb[ci + 1][cg * 4];
                float4 bv2 = *(float4*)&wb[ci + 2][cg * 4];
                float4 bv3 = *(float4*)&wb[ci + 3][cg * 4];
#pragma unroll
                for (int k = 0; k < 4; k++) {
                    float4 av = *(float4*)&inb[pg * 4 + k][ci];
                    acc[k][0] = fmaf(av.x, bv0.x, fmaf(av.y, bv1.x, fmaf(av.z, bv2.x, fmaf(av.w, bv3.x, acc[k][0]))));
                    acc[k][1] = fmaf(av.x, bv0.y, fmaf(av.y, bv1.y, fmaf(av.z, bv2.y, fmaf(av.w, bv3.y, acc[k][1]))));
                    acc[k][2] = fmaf(av.x, bv0.z, fmaf(av.y, bv1.z, fmaf(av.z, bv2.z, fmaf(av.w, bv3.z, acc[k][2]))));
                    acc[k][3] = fmaf(av.x, bv0.w, fmaf(av.y, bv1.w, fmaf(av.z, bv2.w, fmaf(av.w, bv3.w, acc[k][3]))));
                }
            }
            __syncthreads();
        }
    }
    float* outN = out + (size_t)n * LL * CO;
#pragma unroll
    for (int k = 0; k < 4; k++) {
        int p = p0 + pg * 4 + k;
        float4 o;
        o.x = acc[k][0] + bias[co0 + cg * 4 + 0];
        o.y = acc[k][1] + bias[co0 + cg * 4 + 1];
        o.z = acc[k][2] + bias[co0 + cg * 4 + 2];
        o.w = acc[k][3] + bias[co0 + cg * 4 + 3];
        *(float4*)(outN + (size_t)p * CO + co0 + cg * 4) = o;
    }
}

// ---------------------------------------------------------------- fp32 transpose (match embedding) + bf16 copy
__global__ __launch_bounds__(256) void transpose_k(const float* __restrict__ in, float* __restrict__ out,
                                                   unsigned short* __restrict__ out_bf, int R, int Cc)
{
    __shared__ float tl[32][33];
    const int n = blockIdx.z;
    const size_t base = (size_t)n * R * Cc;
    int c0 = blockIdx.x * 32, r0 = blockIdx.y * 32;
    int tx = threadIdx.x & 31, ty0 = threadIdx.x >> 5;
#pragma unroll
    for (int i = 0; i < 32; i += 8)
        tl[ty0 + i][tx] = in[base + (size_t)(r0 + ty0 + i) * Cc + c0 + tx];
    __syncthreads();
#pragma unroll
    for (int i = 0; i < 32; i += 8) {
        float v = tl[tx][ty0 + i];
        size_t o = base + (size_t)(c0 + ty0 + i) * R + r0 + tx;
        out[o] = v;
        out_bf[o] = f2b(v);
    }
}

// ---------------------------------------------------------------- input fp32 -> bf16
__global__ __launch_bounds__(256) void cvt_in_k(const float* __restrict__ in, unsigned short* __restrict__ out)
{
    size_t g = ((size_t)blockIdx.x * 256 + threadIdx.x) * 8;
    float4 v0 = *(const float4*)(in + g);
    float4 v1 = *(const float4*)(in + g + 4);
    u16x8 o;
    o[0] = f2b(v0.x); o[1] = f2b(v0.y); o[2] = f2b(v0.z); o[3] = f2b(v0.w);
    o[4] = f2b(v1.x); o[5] = f2b(v1.y); o[6] = f2b(v1.z); o[7] = f2b(v1.w);
    *(u16x8*)(out + g) = o;
}

// ---------------------------------------------------------------- w_asm [tap][ci][co] fp32 -> wT [tap][co][ci] bf16
__global__ __launch_bounds__(256) void cvt_wT_k(const float* __restrict__ w, unsigned short* __restrict__ wT)
{
    __shared__ float tl[32][33];
    const int tap = blockIdx.z;
    const int c0 = blockIdx.x * 32;
    const int o0 = blockIdx.y * 32;
    const int tx = threadIdx.x & 31, ty0 = threadIdx.x >> 5;
#pragma unroll
    for (int i = 0; i < 32; i += 8)
        tl[ty0 + i][tx] = w[((size_t)tap * 256 + c0 + ty0 + i) * 256 + o0 + tx];
    __syncthreads();
#pragma unroll
    for (int i = 0; i < 32; i += 8)
        wT[((size_t)tap * 256 + o0 + ty0 + i) * 256 + c0 + tx] = f2b(tl[tx][ty0 + i]);
}

// ---------------------------------------------------------------- MFMA conv 3x3 (value path, bf16)
__global__ __launch_bounds__(256) void conv_mfma_k(
    const unsigned short* __restrict__ in_bf, const unsigned short* __restrict__ wT,
    const float* __restrict__ bias, unsigned short* __restrict__ ya_bf)
{
    __shared__ short As[128 * 32];
    __shared__ short Bs[128 * 32];
    const int n = blockIdx.z, p0 = blockIdx.x * 128, co0 = blockIdx.y * 128;
    const int tid = threadIdx.x;
    const int w = tid >> 6, wr = w >> 1, wc = w & 1;
    const int lane = tid & 63, lm = lane & 15, lq = lane >> 4;
    const int r = tid >> 1, hf = tid & 1;
    const int p = p0 + r, py = p / WW, px = p % WW;
    const unsigned short* inN = in_bf + (size_t)n * LL * CHN;

    f32x4 acc[4][4];
#pragma unroll
    for (int a = 0; a < 4; a++)
#pragma unroll
        for (int b = 0; b < 4; b++) acc[a][b] = (f32x4){0.f, 0.f, 0.f, 0.f};

    for (int tap = 0; tap < 9; tap++) {
        const int ky = tap / 3, kx = tap - ky * 3;
        const int sy = py + ky - 1, sx = px + kx - 1;
        const bool valid = ((unsigned)sy < HH) && ((unsigned)sx < WW);
        const unsigned short* asrc = inN + (size_t)(sy * WW + sx) * CHN + hf * 16;
        const unsigned short* bsrc = wT + ((size_t)tap * 256 + co0 + r) * 256 + hf * 16;
        for (int ci0 = 0; ci0 < 256; ci0 += 32) {
            u16x8 av0 = (u16x8){0,0,0,0,0,0,0,0}, av1 = (u16x8){0,0,0,0,0,0,0,0};
            if (valid) {
                av0 = *(const u16x8*)(asrc + ci0);
                av1 = *(const u16x8*)(asrc + ci0 + 8);
            }
            u16x8 bv0 = *(const u16x8*)(bsrc + ci0);
            u16x8 bv1 = *(const u16x8*)(bsrc + ci0 + 8);
            __syncthreads();
            *(u16x8*)&As[r * 32 + hf * 16]     = av0;
            *(u16x8*)&As[r * 32 + hf * 16 + 8] = av1;
            *(u16x8*)&Bs[r * 32 + hf * 16]     = bv0;
            *(u16x8*)&Bs[r * 32 + hf * 16 + 8] = bv1;
            __syncthreads();
            bf16x8 af[4], bf[4];
#pragma unroll
            for (int mt = 0; mt < 4; mt++)
                af[mt] = *(const bf16x8*)&As[(wr * 64 + mt * 16 + lm) * 32 + lq * 8];
#pragma unroll
            for (int nt = 0; nt < 4; nt++)
                bf[nt] = *(const bf16x8*)&Bs[(wc * 64 + nt * 16 + lm) * 32 + lq * 8];
#pragma unroll
            for (int mt = 0; mt < 4; mt++)
#pragma unroll
                for (int nt = 0; nt < 4; nt++)
                    acc[mt][nt] = __builtin_amdgcn_mfma_f32_16x16x32_bf16(af[mt], bf[nt], acc[mt][nt], 0, 0, 0);
        }
    }
    float bv[4];
#pragma unroll
    for (int nt = 0; nt < 4; nt++) bv[nt] = bias[co0 + wc * 64 + nt * 16 + lm];
#pragma unroll
    for (int mt = 0; mt < 4; mt++) {
#pragma unroll
        for (int r4 = 0; r4 < 4; r4++) {
            int row = p0 + wr * 64 + mt * 16 + lq * 4 + r4;
            unsigned short* od = ya_bf + ((size_t)n * LL + row) * CHN + co0 + wc * 64;
#pragma unroll
            for (int nt = 0; nt < 4; nt++)
                od[nt * 16 + lm] = f2b(acc[mt][nt][r4] + bv[nt]);
        }
    }
}

// ---------------------------------------------------------------- bf16 transpose: ya_bf (viewed [256][9216]) -> yaT [9216][256]
__global__ __launch_bounds__(256) void transpose_bf_k(const unsigned short* __restrict__ in,
                                                      unsigned short* __restrict__ out)
{
    __shared__ unsigned short tl[64][65];
    const int n = blockIdx.z;
    const size_t base = (size_t)n * LL * CHN;
    const int t0 = blockIdx.x * 64, e0 = blockIdx.y * 64;
    const int tx = threadIdx.x & 63, ty0 = threadIdx.x >> 6;
#pragma unroll
    for (int i = 0; i < 16; i++) {
        int row = ty0 + i * 4;
        tl[row][tx] = in[base + (size_t)(e0 + row) * LL + t0 + tx];
    }
    __syncthreads();
#pragma unroll
    for (int i = 0; i < 16; i++) {
        int row = ty0 + i * 4;
        out[base + (size_t)(t0 + row) * CHN + e0 + tx] = tl[tx][row];
    }
}

// ---------------------------------------------------------------- hashing: codes + squared norms (fp32!)
__global__ __launch_bounds__(256) void hash_k(const float* __restrict__ xmT, const float* __restrict__ rot,
                                              int* __restrict__ codes, float* __restrict__ ssq)
{
    __shared__ float rs[128 * 68];   // [hi][f], stride 68
    for (int e = threadIdx.x; e < 8192; e += 256) {
        int hi = e >> 6, f = e & 63;
        rs[hi * 68 + f] = rot[f * 128 + hi];
    }
    __syncthreads();
    int g = blockIdx.x * 256 + threadIdx.x;
    int n = g / LL, t = g % LL;
    float4 x4[16];
    const float* src = xmT + (size_t)g * CC;
#pragma unroll
    for (int f4 = 0; f4 < 16; f4++) x4[f4] = *(const float4*)(src + f4 * 4);
    float ss = 0.f;
#pragma unroll
    for (int f4 = 0; f4 < 16; f4++)
        ss += x4[f4].x * x4[f4].x + x4[f4].y * x4[f4].y + x4[f4].z * x4[f4].z + x4[f4].w * x4[f4].w;
    ssq[g] = ss;
    for (int h = 0; h < NHASH; h++) {
        float bp = -1e30f, bn = -1e30f;
        int ip = 0, inn = 0;
        for (int i = 0; i < 32; i++) {
            const float* rr = &rs[(h * 32 + i) * 68];
            float d0 = 0.f, d1 = 0.f, d2 = 0.f, d3 = 0.f;
#pragma unroll
            for (int f4 = 0; f4 < 16; f4++) {
                float4 r4 = *(const float4*)(rr + f4 * 4);
                d0 = fmaf(x4[f4].x, r4.x, d0);
                d1 = fmaf(x4[f4].y, r4.y, d1);
                d2 = fmaf(x4[f4].z, r4.z, d2);
                d3 = fmaf(x4[f4].w, r4.w, d3);
            }
            float d = (d0 + d1) + (d2 + d3);
            if (d > bp) { bp = d; ip = i; }
            if (-d > bn) { bn = -d; inn = i; }
        }
        int code = (bp >= bn) ? ip : (32 + inn);
        codes[(size_t)n * NJ + h * LL + t] = code + h * HBK;
    }
}

// ---------------------------------------------------------------- stable counting sort (256 buckets)
__global__ __launch_bounds__(256) void sort_hist_k(const int* __restrict__ codes, int* __restrict__ hist,
                                                   int* __restrict__ rank)
{
    __shared__ int lc[256];
    __shared__ int lh[256];
    const int n = blockIdx.y, seg = blockIdx.x, tid = threadIdx.x;
    int j = seg * 256 + tid;
    int c = codes[(size_t)n * NJ + j];
    lc[tid] = c;
    lh[tid] = 0;
    __syncthreads();
    int r = 0;
    for (int q = 0; q < tid; q++) r += (lc[q] == c) ? 1 : 0;
    atomicAdd(&lh[c], 1);
    __syncthreads();
    rank[(size_t)n * NJ + j] = r;
    hist[(size_t)n * NJ + tid * 144 + seg] = lh[tid];
}

__global__ __launch_bounds__(256) void sort_scan_k(int* __restrict__ hist)
{
    const int n = blockIdx.x;
    const int key = threadIdx.x;
    int* hn = hist + (size_t)n * NJ;
    int sum = 0;
    for (int s = 0; s < 144; s++) sum += hn[key * 144 + s];
    __shared__ int tot[256];
    tot[key] = sum;
    __syncthreads();
    int excl = 0;
    for (int q = 0; q < key; q++) excl += tot[q];
    int run = excl;
    for (int s = 0; s < 144; s++) { int v = hn[key * 144 + s]; hn[key * 144 + s] = run; run += v; }
}

__global__ __launch_bounds__(256) void sort_scatter_k(const int* __restrict__ codes, const int* __restrict__ rank,
                                                      const int* __restrict__ hist, int* __restrict__ sidx,
                                                      int* __restrict__ undo)
{
    const int n = blockIdx.y, seg = blockIdx.x, tid = threadIdx.x;
    int j = seg * 256 + tid;
    int c = codes[(size_t)n * NJ + j];
    int dest = hist[(size_t)n * NJ + c * 144 + seg] + rank[(size_t)n * NJ + j];
    sidx[(size_t)n * NJ + dest] = j;
    undo[(size_t)n * NJ + j] = dest;
}

// ---------------------------------------------------------------- MFMA attention v2 (+ NaN fix: P pad cols zeroed once)
// V gathered from global (no LDS); raw-K + post-scale; lsum via ones-MFMA; cc=0 reuses Qs as K.
#define QSTR 72     // Q/K row stride in shorts
#define PSTR 168    // P row stride in shorts
__global__ __launch_bounds__(1024, 4) void attn_mfma_k(
    const unsigned short* __restrict__ xmT_bf, const unsigned short* __restrict__ yaT,
    const float* __restrict__ ssq, const int* __restrict__ sidx,
    unsigned short* __restrict__ Osort, float* __restrict__ bs)
{
    __shared__ short Qs[144 * QSTR];
    __shared__ short UN[144 * PSTR];   // Ks (stride QSTR) for cc>0, overlaid by P (stride PSTR)
    __shared__ int   tIdx[432];
    __shared__ int   voff[432];
    __shared__ float nfs[432];
    __shared__ float qlen[432];
    __shared__ float lsum[144];
    __shared__ float linv[144];

    const int k = blockIdx.x, h = blockIdx.y, n = blockIdx.z;
    const int tid = threadIdx.x;
    const int w = tid >> 6, lane = tid & 63;
    const int lm = lane & 15, lq = lane >> 4;
    const size_t sbase = (size_t)n * NJ + (size_t)h * LL;

    if (tid < 432) {
        int cc = tid / CHK, rr = tid - cc * CHK;
        int c = (cc == 0) ? k : (cc == 1 ? (k + NCHUNK - 1) & (NCHUNK - 1) : (k + 1) & (NCHUNK - 1));
        int j = sidx[sbase + c * CHK + rr];
        int t = j % LL;
        tIdx[tid] = t;
        voff[tid] = t * (CHN * 2);
        float m = fmaxf(ssq[(size_t)n * LL + t], 5e-5f);
        float nf = rsqrtf(m);
        nfs[tid] = nf;
        qlen[tid] = m * nf;   // sqrt(m) = |q| clamped
    }
    __syncthreads();

    // stage Q rows (raw bf16)
    for (int e = tid; e < 1152; e += 1024) {
        int r = e >> 3, j8 = e & 7;
        u16x8 v = *(const u16x8*)(xmT_bf + ((size_t)n * LL + tIdx[r]) * CC + j8 * 8);
        *(u16x8*)&Qs[r * QSTR + j8 * 8] = v;
    }
    // NaN fix: zero P pad columns 144..159 for all 144 rows ONCE. Later overwrites of
    // these addresses are only finite Ks staging data (rows <= 60), whose contribution
    // is exactly 0 under the vfrag/onesL masks. Without this, initial LDS garbage can
    // be a bf16 NaN pattern and 0*NaN = NaN poisons the PV/lsum accumulators.
    for (int e = tid; e < 2304; e += 1024) {
        int r = e >> 4, c = 144 + (e & 15);
        UN[r * PSTR + c] = 0;
    }

    const char* vbase = (const char*)(yaT + (size_t)n * LL * CHN + w * 16 + lm);
    f32x4 accO[9];
#pragma unroll
    for (int mt = 0; mt < 9; mt++) accO[mt] = (f32x4){0.f, 0.f, 0.f, 0.f};
    f32x4 accL = (f32x4){0.f, 0.f, 0.f, 0.f};
    bf16x8 onesF, onesL;
#pragma unroll
    for (int i = 0; i < 8; i++) {
        onesF[i] = (short)0x3F80;
        onesL[i] = (lq < 2) ? (short)0x3F80 : (short)0;   // mask pad keys 144..159 (k-step 4, lq>=2)
    }
    float pbuf[6][4];

    __syncthreads();   // Qs + pad zeros ready

    for (int cc = 0; cc < 3; cc++) {
        const int c144 = cc * CHK;
        if (cc > 0) {
            __syncthreads();   // prev chunk's P reads (PV + lsum) done — UN reusable
            for (int e = tid; e < 1152; e += 1024) {
                int r = e >> 3, j8 = e & 7;
                u16x8 v = *(const u16x8*)(xmT_bf + ((size_t)n * LL + tIdx[c144 + r]) * CC + j8 * 8);
                *(u16x8*)&UN[r * QSTR + j8 * 8] = v;
            }
        }
        // V B-frag gathers from global — issued early, consumed after QK (latency hidden)
        bf16x8 vfrag[5];
#pragma unroll
        for (int ks = 0; ks < 5; ks++) {
            int kb = ks * 32 + lq * 8;
            if (kb < 144) {
                int4 o0 = *(const int4*)&voff[c144 + kb];
                int4 o1 = *(const int4*)&voff[c144 + kb + 4];
                vfrag[ks][0] = (short)*(const unsigned short*)(vbase + o0.x);
                vfrag[ks][1] = (short)*(const unsigned short*)(vbase + o0.y);
                vfrag[ks][2] = (short)*(const unsigned short*)(vbase + o0.z);
                vfrag[ks][3] = (short)*(const unsigned short*)(vbase + o0.w);
                vfrag[ks][4] = (short)*(const unsigned short*)(vbase + o1.x);
                vfrag[ks][5] = (short)*(const unsigned short*)(vbase + o1.y);
                vfrag[ks][6] = (short)*(const unsigned short*)(vbase + o1.z);
                vfrag[ks][7] = (short)*(const unsigned short*)(vbase + o1.w);
            } else {
                vfrag[ks] = (bf16x8){0, 0, 0, 0, 0, 0, 0, 0};
            }
        }
        if (cc > 0) __syncthreads();   // Ks ready

        // QK (B^T GEMM) + exp; raw scores post-scaled by key norm
        const short* Bsrc = (cc == 0) ? Qs : UN;
        int li = 0;
        for (int tt = w; tt < 81; tt += 16, li++) {
            int mt = tt / 9, nt = tt - mt * 9;
            f32x4 c = {0.f, 0.f, 0.f, 0.f};
#pragma unroll
            for (int ks = 0; ks < 2; ks++) {
                bf16x8 a = *(const bf16x8*)&Qs[(mt * 16 + lm) * QSTR + ks * 32 + lq * 8];
                bf16x8 b = *(const bf16x8*)&Bsrc[(nt * 16 + lm) * QSTR + ks * 32 + lq * 8];
                c = __builtin_amdgcn_mfma_f32_16x16x32_bf16(a, b, c, 0, 0, 0);
            }
            float nfk = nfs[c144 + nt * 16 + lm];
#pragma unroll
            for (int r = 0; r < 4; r++) {
                int mrow = mt * 16 + lq * 4 + r;
                float p = __expf(fmaf(c[r], nfk, -qlen[mrow]));
                if (cc == 0) UN[mrow * PSTR + nt * 16 + lm] = (short)f2b(p);
                else pbuf[li][r] = p;
            }
        }
        if (cc > 0) {
            __syncthreads();   // all Ks reads done — safe to overlay P
            li = 0;
            for (int tt = w; tt < 81; tt += 16, li++) {
                int mt = tt / 9, nt = tt - mt * 9;
#pragma unroll
                for (int r = 0; r < 4; r++)
                    UN[(mt * 16 + lq * 4 + r) * PSTR + nt * 16 + lm] = (short)f2b(pbuf[li][r]);
            }
        }
        __syncthreads();   // P ready (pad cols 144..159: zero or finite-K — masked to exact 0)

        // lsum via ones-MFMA (waves 0..8, mt = w)
        if (w < 9) {
#pragma unroll
            for (int ks = 0; ks < 5; ks++) {
                bf16x8 a = *(const bf16x8*)&UN[(w * 16 + lm) * PSTR + ks * 32 + lq * 8];
                accL = __builtin_amdgcn_mfma_f32_16x16x32_bf16(a, (ks == 4) ? onesL : onesF, accL, 0, 0, 0);
            }
        }
        // PV: 9 m-tiles, V frags in registers
#pragma unroll
        for (int mt = 0; mt < 9; mt++) {
            f32x4 c = accO[mt];
#pragma unroll
            for (int ks = 0; ks < 5; ks++) {
                bf16x8 a = *(const bf16x8*)&UN[(mt * 16 + lm) * PSTR + ks * 32 + lq * 8];
                c = __builtin_amdgcn_mfma_f32_16x16x32_bf16(a, vfrag[ks], c, 0, 0, 0);
            }
            accO[mt] = c;
        }
    }

    __syncthreads();
    if (w < 9 && lm == 0) {
#pragma unroll
        for (int r = 0; r < 4; r++) lsum[w * 16 + lq * 4 + r] = accL[r];
    }
    __syncthreads();
    if (tid < 144) {
        float l = lsum[tid];
        linv[tid] = 1.0f / l;
        bs[sbase + tIdx[tid]] = qlen[tid] + __logf(l);
    }
    __syncthreads();

#pragma unroll
    for (int mt = 0; mt < 9; mt++) {
        f32x4 c = accO[mt];
#pragma unroll
        for (int r = 0; r < 4; r++) {
            int mrow = mt * 16 + lq * 4 + r;
            Osort[(sbase + (size_t)k * CHK + mrow) * CHN + w * 16 + lm] = f2b(c[r] * linv[mrow]);
        }
    }
}

// ---------------------------------------------------------------- combine (4 hashes, inline softmax) + transpose + residual
__global__ __launch_bounds__(256) void combfin_k(
    const unsigned short* __restrict__ Osort, const float* __restrict__ bs,
    const int* __restrict__ undo, const float* __restrict__ inp, float* __restrict__ out)
{
    __shared__ float ac[32][260];
    __shared__ int   uS[4][32];
    __shared__ float pS[4][32];
    const int n = blockIdx.y;
    const int t0 = blockIdx.x * 32;
    const int tid = threadIdx.x;
    if (tid < 128) {
        int hh = tid >> 5, tt = tid & 31;
        size_t idx = (size_t)n * NJ + (size_t)hh * LL + t0 + tt;
        uS[hh][tt] = undo[idx];
        pS[hh][tt] = bs[idx];
    }
    __syncthreads();
    if (tid < 32) {
        float b0 = pS[0][tid], b1 = pS[1][tid], b2 = pS[2][tid], b3 = pS[3][tid];
        float mx = fmaxf(fmaxf(b0, b1), fmaxf(b2, b3));
        float e0 = __expf(b0 - mx), e1 = __expf(b1 - mx), e2 = __expf(b2 - mx), e3 = __expf(b3 - mx);
        float inv = 1.f / (e0 + e1 + e2 + e3);
        pS[0][tid] = e0 * inv; pS[1][tid] = e1 * inv; pS[2][tid] = e2 * inv; pS[3][tid] = e3 * inv;
    }
    __syncthreads();
    const int g = tid & 63, tq = tid >> 6;
    for (int tt8 = 0; tt8 < 8; tt8++) {
        int t = tq * 8 + tt8;
        float a0 = 0.f, a1 = 0.f, a2 = 0.f, a3 = 0.f;
#pragma unroll
        for (int hh = 0; hh < 4; hh++) {
            int row = uS[hh][t];
            float p = pS[hh][t];
            ushort4 u = *(const ushort4*)&Osort[((size_t)n * NJ + row) * CHN + g * 4];
            a0 = fmaf(p, b2f(u.x), a0);
            a1 = fmaf(p, b2f(u.y), a1);
            a2 = fmaf(p, b2f(u.z), a2);
            a3 = fmaf(p, b2f(u.w), a3);
        }
        *(float4*)&ac[t][g * 4] = make_float4(a0, a1, a2, a3);
    }
    __syncthreads();
    const int tp = tid & 31, er = tid >> 5;
    const float* inN = inp + (size_t)n * LL * CHN;
    float* outN = out + (size_t)n * LL * CHN;
    for (int it = 0; it < 32; it++) {
        int e = er + it * 8;
        size_t o = (size_t)e * LL + t0 + tp;
        outN[o] = ac[tp][e] * 0.1f + inN[o];
    }
}

// ---------------------------------------------------------------- launch
extern "C" void kernel_launch(void* const* d_in, const int* in_sizes, int n_in,
                              void* d_out, int out_size, void* d_ws, size_t ws_size,
                              hipStream_t stream)
{
    (void)in_sizes; (void)n_in; (void)out_size; (void)ws_size;
    const float* input   = (const float*)d_in[0];
    const float* w_match = (const float*)d_in[1];
    const float* b_match = (const float*)d_in[2];
    const float* w_asm   = (const float*)d_in[3];
    const float* b_asm   = (const float*)d_in[4];
    const float* rot     = (const float*)d_in[5];
    float* out = (float*)d_out;

    char* ws = (char*)d_ws;
    size_t off = 0;
    auto alloc = [&](size_t bytes) -> void* {
        void* p = ws + off;
        off += (bytes + 255) & ~(size_t)255;
        return p;
    };
    unsigned short* in_bf  = (unsigned short*)alloc((size_t)NB * LL * CHN * 2);
    unsigned short* wT_bf  = (unsigned short*)alloc((size_t)9 * CHN * CHN * 2);
    unsigned short* ya_bf  = (unsigned short*)alloc((size_t)NB * LL * CHN * 2);
    unsigned short* yaT    = (unsigned short*)alloc((size_t)NB * LL * CHN * 2);
    float* xm     = (float*)alloc((size_t)NB * LL * CC * 4);
    float* xmT    = (float*)alloc((size_t)NB * LL * CC * 4);
    unsigned short* xmT_bf = (unsigned short*)alloc((size_t)NB * LL * CC * 2);
    float* ssq    = (float*)alloc((size_t)NB * LL * 4);
    int*   codes  = (int*)  alloc((size_t)NB * NJ * 4);
    int*   rank   = (int*)  alloc((size_t)NB * NJ * 4);
    int*   hist   = (int*)  alloc((size_t)NB * NJ * 4);
    int*   sidx   = (int*)  alloc((size_t)NB * NJ * 4);
    int*   undo   = (int*)  alloc((size_t)NB * NJ * 4);
    float* bs     = (float*)alloc((size_t)NB * NJ * 4);
    unsigned short* Osort = (unsigned short*)alloc((size_t)NB * NJ * CHN * 2);

    // match path (fp32 — feeds hashing)
    conv3x3_k<<<dim3(144, 1, NB), 256, 0, stream>>>(input, w_match, b_match, xm, CC);
    transpose_k<<<dim3(288, 2, NB), 256, 0, stream>>>(xm, xmT, xmT_bf, CC, LL);
    // value path (bf16 MFMA)
    cvt_in_k<<<dim3(4608), 256, 0, stream>>>(input, in_bf);
    cvt_wT_k<<<dim3(8, 8, 9), 256, 0, stream>>>(w_asm, wT_bf);
    conv_mfma_k<<<dim3(72, 2, NB), 256, 0, stream>>>(in_bf, wT_bf, b_asm, ya_bf);
    transpose_bf_k<<<dim3(144, 4, NB), 256, 0, stream>>>(ya_bf, yaT);
    // hashing + sort
    hash_k<<<dim3(144), 256, 0, stream>>>(xmT, rot, codes, ssq);
    sort_hist_k<<<dim3(144, NB), 256, 0, stream>>>(codes, hist, rank);
    sort_scan_k<<<dim3(NB), 256, 0, stream>>>(hist);
    sort_scatter_k<<<dim3(144, NB), 256, 0, stream>>>(codes, rank, hist, sidx, undo);
    // attention + combine
    attn_mfma_k<<<dim3(NCHUNK, NHASH, NB), 1024, 0, stream>>>(xmT_bf, yaT, ssq, sidx, Osort, bs);
    combfin_k<<<dim3(288, NB), 256, 0, stream>>>(Osort, bs, undo, input, out);
}